// Round 1
// baseline (390.282 us; speedup 1.0000x reference)
//
#include <hip/hip_runtime.h>

typedef unsigned short u16;
typedef unsigned int   u32;

typedef __bf16 bf16x8 __attribute__((ext_vector_type(8)));
typedef float  f32x4  __attribute__((ext_vector_type(4)));

typedef const __attribute__((address_space(1))) u32 GAS;
typedef __attribute__((address_space(3))) u32 LAS;

__device__ __forceinline__ u16 f2bf(float f) {
  u32 u = __builtin_bit_cast(u32, f);
  return (u16)((u + 0x7FFFu + ((u >> 16) & 1u)) >> 16);
}

// ---------------------------------------------------------------------------
// X3[kblk][m][8] bf16, kblk = k/8, m in [0,4096), k in [0,6144):
//   seg0 [xr | hr], seg1 [xi | hi], seg2 [xr+xi | hr+hi]
// ---------------------------------------------------------------------------
__global__ __launch_bounds__(256) void build_x_k(
    const float* __restrict__ inp, const float* __restrict__ h,
    u16* __restrict__ X3) {
  __shared__ float t[64 * 65];  // t[k][m], pitch 65
  const int tid = threadIdx.x;
  const int tx = tid & 15, ty = tid >> 4;
  const int m0 = blockIdx.y * 64, k0 = blockIdx.x * 64;
  const int sel = k0 >> 10;          // uniform per block
  const int kc = k0 & 1023;
  const float* s1 = (sel == 0 || sel == 2 || sel == 4) ? inp : h;
  const int c1 = (sel == 2 || sel == 3) ? (1024 + kc) : kc;
  const bool pair = (sel >= 4);      // add column c1 + 1024 of same source
#pragma unroll
  for (int rr = 0; rr < 4; ++rr) {
    const int m = rr * 16 + ty;
    float4 v = *(const float4*)&s1[(size_t)(m0 + m) * 2048 + c1 + tx * 4];
    if (pair) {
      const float4 w = *(const float4*)&s1[(size_t)(m0 + m) * 2048 + c1 + 1024 + tx * 4];
      v.x += w.x; v.y += w.y; v.z += w.z; v.w += w.w;
    }
    t[(tx * 4 + 0) * 65 + m] = v.x;
    t[(tx * 4 + 1) * 65 + m] = v.y;
    t[(tx * 4 + 2) * 65 + m] = v.z;
    t[(tx * 4 + 3) * 65 + m] = v.w;
  }
  __syncthreads();
#pragma unroll
  for (int rep = 0; rep < 2; ++rep) {
    const int cell = rep * 256 + tid;       // 512 cells: kblk(8) x m(64)
    const int kblk = cell >> 6, m = cell & 63;
    union { u16 s[8]; uint4 v; } tmp;
#pragma unroll
    for (int i = 0; i < 8; ++i) tmp.s[i] = f2bf(t[(kblk * 8 + i) * 65 + m]);
    *(uint4*)&X3[((size_t)(k0 / 8 + kblk) * 4096 + m0 + m) * 8] = tmp.v;
  }
}

// ---------------------------------------------------------------------------
// W3[kblk][n][8] bf16, rows k in [0,6144): seg0 [Kr;Rr], seg1 [Ki;Ri],
// seg2 [Kr-Ki; Rr-Ri].  Cols n = (j>>4)*64 + g*16 + (j&15), j in [0,1024).
// ---------------------------------------------------------------------------
__global__ __launch_bounds__(256) void build_w_k(
    const float* __restrict__ Kr, const float* __restrict__ Ki,
    const float* __restrict__ Rr, const float* __restrict__ Ri,
    u16* __restrict__ W3) {
  __shared__ float t[4 * 1032];  // [g][k(64)][jlo(16)], per-g pitch 1032
  const int tid = threadIdx.x;
  const int tx = tid & 15, ty = tid >> 4;
  const int jhi = blockIdx.y;          // [0,64): 16-j group
  const int k0 = blockIdx.x * 64;      // [0,6144)
  const int sel = k0 >> 10;            // 0:Kr 1:Rr 2:Ki 3:Ri 4:Kr-Ki 5:Rr-Ri
  const int krow = k0 & 1023;
  const int jbase = jhi * 16;
  const float* sA = (sel == 0) ? Kr : (sel == 1) ? Rr : (sel == 2) ? Ki
                  : (sel == 3) ? Ri : (sel == 4) ? Kr : Rr;
  const float* sB = (sel == 4) ? Ki : (sel == 5) ? Ri : nullptr;
#pragma unroll
  for (int g = 0; g < 4; ++g) {
    const int cs = g * 1024 + jbase + tx;
#pragma unroll
    for (int rr = 0; rr < 4; ++rr) {
      const int k = rr * 16 + ty;
      float v = sA[(size_t)(krow + k) * 4096 + cs];
      if (sel >= 4) v -= sB[(size_t)(krow + k) * 4096 + cs];
      t[g * 1032 + k * 16 + tx] = v;
    }
  }
  __syncthreads();
#pragma unroll
  for (int rep = 0; rep < 2; ++rep) {
    const int cell = rep * 256 + tid;       // 512 cells: kblk(8) x n(64)
    const int kblk = cell >> 6, n = cell & 63;
    const int g = n >> 4, jlo = n & 15;
    union { u16 s[8]; uint4 v; } tmp;
#pragma unroll
    for (int i = 0; i < 8; ++i)
      tmp.s[i] = f2bf(t[g * 1032 + (kblk * 8 + i) * 16 + jlo]);
    *(uint4*)&W3[((size_t)(k0 / 8 + kblk) * 4096 + (size_t)jhi * 64 + n) * 8] = tmp.v;
  }
}

// ---------------------------------------------------------------------------
// Fused Gauss-GEMM + CLSTM epilogue — T3 phase-split schedule (this round).
//   t in [0,32):  bankA += P1;  t in [32,64): bankB += P2;
//   merge: A = P1+P2 (zr-pre), B = P2-P1;  t in [64,96): bankB += P3 -> zi-pre
// BM=128, BN=256 pcols, BK=64, ring-3 LDS (3x48 KiB = 144 KiB), 8 waves
// (2M x 4N), 16x16x32 MFMA.
// Each slot = 2 phases (one per ks).  Phase = { 8x ds_read_b128, issue 3
// global_load_lds of slot t+2, [phase B: counted vmcnt(6) draining slot
// t+1's 6 loads — never 0 mid-loop], s_barrier, lgkmcnt(0)+sched_barrier(0),
// setprio(1), 16 MFMA, setprio(0), s_barrier }.  In-flight ledger unchanged:
// 12 outstanding steady-state, drain to 6 once per slot.  T1 XCD swizzle:
// mb = wg&31 (A streams, 32/XCD), nb = wg>>5 (B shared, 2/XCD).
// acc = 2 banks x 64 = 128 regs (no spill).
// ---------------------------------------------------------------------------
#define KT 96  // K slots (6144 / 64); bank switches at 32, 64

#define PHASE(ACC, KS, HALF)                                                \
  {                                                                         \
    bf16x8 af[4], bfr[4];                                                   \
    _Pragma("unroll")                                                       \
    for (int mf = 0; mf < 4; ++mf)                                          \
      af[mf] = *(const bf16x8*)&buf[aoff + (KS) * 4096 + mf * 128];         \
    _Pragma("unroll")                                                       \
    for (int nf = 0; nf < 4; ++nf)                                          \
      bfr[nf] = *(const bf16x8*)&buf[boff + (KS) * 8192 + nf * 128];        \
    if (t + 2 < KT) stage3(t + 2, stb, HALF);                               \
    if (HALF) {                                                             \
      if (t + 1 == KT - 1)                                                  \
        asm volatile("s_waitcnt vmcnt(0)" ::: "memory");                    \
      else if (t + 1 < KT - 1)                                              \
        asm volatile("s_waitcnt vmcnt(6)" ::: "memory");                    \
    }                                                                       \
    __builtin_amdgcn_s_barrier();                                           \
    asm volatile("s_waitcnt lgkmcnt(0)" ::: "memory");                      \
    __builtin_amdgcn_sched_barrier(0);                                      \
    __builtin_amdgcn_s_setprio(1);                                          \
    _Pragma("unroll")                                                       \
    for (int mf = 0; mf < 4; ++mf)                                          \
      _Pragma("unroll")                                                     \
      for (int nf = 0; nf < 4; ++nf)                                        \
        ACC[mf][nf] = __builtin_amdgcn_mfma_f32_16x16x32_bf16(              \
            af[mf], bfr[nf], ACC[mf][nf], 0, 0, 0);                         \
    __builtin_amdgcn_s_setprio(0);                                          \
    __builtin_amdgcn_s_barrier();                                           \
  }

__global__ __launch_bounds__(512, 2) void clstm_gemm_k(
    const u16* __restrict__ X3, const u16* __restrict__ W3,
    const float* __restrict__ cprev, const float* __restrict__ rb,
    const float* __restrict__ ib, float* __restrict__ out) {
  __shared__ __align__(16) u16 lds[3][24576];  // 3 bufs x 48 KiB = 144 KiB
  const int tid = threadIdx.x;
  const int lane = tid & 63, wave = tid >> 6;
  const int wr = wave >> 2, wc = wave & 3;  // 2M x 4N wave grid
  const int orig = blockIdx.x;
  const int wg = (orig & 7) * 64 + (orig >> 3);  // T1 (512 % 8 == 0)
  const int mb = wg & 31, nb = wg >> 5;  // A streams (32/XCD), B shared (2/XCD)
  const int m0 = mb * 128, n0 = nb * 256;

  f32x4 a1[4][4] = {}, a2[4][4] = {};

  // stage half of slot t (3 of 6 1-KiB chunks per wave) into ring buffer bi
  auto stage3 = [&](int t, int bi, int half) {
    u16* buf = &lds[bi][0];
    const size_t kb0 = (size_t)t * 8;
#pragma unroll
    for (int i = half * 3; i < half * 3 + 3; ++i) {
      const int c = wave * 6 + i;
      if (c < 16) {  // A tile: [kblk(8)][m(128)][8]
        const int kblk = c >> 1, half2 = c & 1;
        const u16* g = X3 + ((kb0 + kblk) * 4096 + (size_t)(m0 + half2 * 64 + lane)) * 8;
        __builtin_amdgcn_global_load_lds((GAS*)g, (LAS*)&buf[(kblk * 128 + half2 * 64) * 8],
                                         16, 0, 0);
      } else {       // B tile: [kblk(8)][n(256)][8] at u16 offset 8192
        const int cc = c - 16, kblk = cc >> 2, grp = cc & 3;
        const u16* g = W3 + ((kb0 + kblk) * 4096 + (size_t)(n0 + grp * 64 + lane)) * 8;
        __builtin_amdgcn_global_load_lds((GAS*)g,
                                         (LAS*)&buf[8192 + (kblk * 256 + grp * 64) * 8],
                                         16, 0, 0);
      }
    }
  };

  const int hi = lane >> 4, lo = lane & 15;
  const int aoff = (hi * 128 + wr * 64 + lo) * 8;           // + ks*4096 + mf*128
  const int boff = 8192 + (hi * 256 + wc * 64 + lo) * 8;    // + ks*8192 + nf*128

  // ---- prologue: 2 slots in flight, retire slot 0 ----
  stage3(0, 0, 0); stage3(0, 0, 1);
  stage3(1, 1, 0); stage3(1, 1, 1);
  asm volatile("s_waitcnt vmcnt(6)" ::: "memory");
  __builtin_amdgcn_s_barrier();          // slot 0 visible to all waves
  int cb = 0;  // ring index of current slot (t % 3), advanced manually

  for (int t = 0; t < 32; ++t) {   // segment 1 -> bankA = P1
    int stb = cb + 2; if (stb >= 3) stb -= 3;
    const u16* buf = &lds[cb][0];
    PHASE(a1, 0, 0)
    PHASE(a1, 1, 1)
    ++cb; if (cb == 3) cb = 0;
  }
  for (int t = 32; t < 64; ++t) {  // segment 2 -> bankB = P2
    int stb = cb + 2; if (stb >= 3) stb -= 3;
    const u16* buf = &lds[cb][0];
    PHASE(a2, 0, 0)
    PHASE(a2, 1, 1)
    ++cb; if (cb == 3) cb = 0;
  }
  // ---- one-time merge: A = P1+P2 (zr-pre), B = P2-P1 ----
#pragma unroll
  for (int mf = 0; mf < 4; ++mf)
#pragma unroll
    for (int nf = 0; nf < 4; ++nf) {
      const f32x4 t0 = a1[mf][nf];
      a1[mf][nf] = t0 + a2[mf][nf];
      a2[mf][nf] = a2[mf][nf] - t0;
    }
  for (int t = 64; t < KT; ++t) {  // segment 3 -> bankB += P3 = zi-pre
    int stb = cb + 2; if (stb >= 3) stb -= 3;
    const u16* buf = &lds[cb][0];
    PHASE(a2, 0, 0)
    PHASE(a2, 1, 1)
    ++cb; if (cb == 3) cb = 0;
  }

  // ---- fused CLSTM epilogue: zr = a1+rb, zi = a2+ib (lane-local) ----
  const int j = (nb * 4 + wc) * 16 + lo;   // output column in [0,1024)
  float rbias[4], ibias[4];
#pragma unroll
  for (int g = 0; g < 4; ++g) {
    rbias[g] = rb[g * 1024 + j];
    ibias[g] = ib[g * 1024 + j];
  }
#pragma unroll
  for (int mf = 0; mf < 4; ++mf) {
    const int rowb = m0 + wr * 64 + mf * 16 + hi * 4;
#pragma unroll
    for (int r = 0; r < 4; ++r) {
      const size_t row = (size_t)(rowb + r);
      // real half: output cols [0,1024)
      {
        const float z0 = a1[mf][0][r] + rbias[0];
        const float z1 = a1[mf][1][r] + rbias[1];
        const float z2 = a1[mf][2][r] + rbias[2];
        const float z3 = a1[mf][3][r] + rbias[3];
        const float ig = fminf(fmaxf(0.2f * z0 + 0.5f, 0.0f), 1.0f);
        const float fg = fminf(fmaxf(0.2f * z1 + 0.5f, 0.0f), 1.0f);
        const float og = fminf(fmaxf(0.2f * z3 + 0.5f, 0.0f), 1.0f);
        const float cp = cprev[row * 2048 + j];
        const float cn = fg * cp + ig * tanhf(z2);
        const float hn = og * tanhf(cn);
        out[row * 2048 + j] = hn;
        out[(size_t)8388608 + row * 2048 + j] = cn;
      }
      // imaginary half: output cols [1024,2048)
      {
        const float z0 = a2[mf][0][r] + ibias[0];
        const float z1 = a2[mf][1][r] + ibias[1];
        const float z2 = a2[mf][2][r] + ibias[2];
        const float z3 = a2[mf][3][r] + ibias[3];
        const float ig = fminf(fmaxf(0.2f * z0 + 0.5f, 0.0f), 1.0f);
        const float fg = fminf(fmaxf(0.2f * z1 + 0.5f, 0.0f), 1.0f);
        const float og = fminf(fmaxf(0.2f * z3 + 0.5f, 0.0f), 1.0f);
        const float cp = cprev[row * 2048 + 1024 + j];
        const float cn = fg * cp + ig * tanhf(z2);
        const float hn = og * tanhf(cn);
        out[row * 2048 + 1024 + j] = hn;
        out[(size_t)8388608 + row * 2048 + 1024 + j] = cn;
      }
    }
  }
}

extern "C" void kernel_launch(void* const* d_in, const int* in_sizes, int n_in,
                              void* d_out, int out_size, void* d_ws, size_t ws_size,
                              hipStream_t stream) {
  const float* inputs = (const float*)d_in[0];
  const float* h_tm1  = (const float*)d_in[1];
  const float* c_tm1  = (const float*)d_in[2];
  const float* Kr     = (const float*)d_in[3];
  const float* Ki     = (const float*)d_in[4];
  const float* Rr     = (const float*)d_in[5];
  const float* Ri     = (const float*)d_in[6];
  const float* rb     = (const float*)d_in[7];
  const float* ib     = (const float*)d_in[8];
  float* out = (float*)d_out;

  u16* X3 = (u16*)d_ws;                       // 768*4096*8 u16 = 48 MiB
  u16* W3 = X3 + (size_t)768 * 4096 * 8;      // 768*4096*8 u16 = 48 MiB

  build_x_k<<<dim3(96, 64), 256, 0, stream>>>(inputs, h_tm1, X3);
  build_w_k<<<dim3(96, 64), 256, 0, stream>>>(Kr, Ki, Rr, Ri, W3);
  clstm_gemm_k<<<dim3(512, 1), 512, 0, stream>>>(X3, W3, c_tm1, rb, ib, out);
}

// Round 2
// 369.091 us; speedup vs baseline: 1.0574x; 1.0574x over previous
//
#include <hip/hip_runtime.h>

typedef unsigned short u16;
typedef unsigned int   u32;

typedef __bf16 bf16x8 __attribute__((ext_vector_type(8)));
typedef float  f32x4  __attribute__((ext_vector_type(4)));

typedef const __attribute__((address_space(1))) u32 GAS;
typedef __attribute__((address_space(3))) u32 LAS;

__device__ __forceinline__ u16 f2bf(float f) {
  u32 u = __builtin_bit_cast(u32, f);
  return (u16)((u + 0x7FFFu + ((u >> 16) & 1u)) >> 16);
}

// ---------------------------------------------------------------------------
// X4[kblk][m][8] bf16, k in [0,4096): [xr | xi | hr | hi] (1024 each)
// ---------------------------------------------------------------------------
__global__ __launch_bounds__(256) void build_x_k(
    const float* __restrict__ inp, const float* __restrict__ h,
    u16* __restrict__ X4) {
  __shared__ float t[64 * 65];  // t[k][m], pitch 65
  const int tid = threadIdx.x;
  const int tx = tid & 15, ty = tid >> 4;
  const int m0 = blockIdx.y * 64, k0 = blockIdx.x * 64;
  const int sel = k0 >> 10;          // 0:xr 1:xi 2:hr 3:hi
  const int kc = k0 & 1023;
  const float* s1 = (sel < 2) ? inp : h;
  const int c1 = (sel & 1) * 1024 + kc;
#pragma unroll
  for (int rr = 0; rr < 4; ++rr) {
    const int m = rr * 16 + ty;
    float4 v = *(const float4*)&s1[(size_t)(m0 + m) * 2048 + c1 + tx * 4];
    t[(tx * 4 + 0) * 65 + m] = v.x;
    t[(tx * 4 + 1) * 65 + m] = v.y;
    t[(tx * 4 + 2) * 65 + m] = v.z;
    t[(tx * 4 + 3) * 65 + m] = v.w;
  }
  __syncthreads();
#pragma unroll
  for (int rep = 0; rep < 2; ++rep) {
    const int cell = rep * 256 + tid;       // 512 cells: kblk(8) x m(64)
    const int kblk = cell >> 6, m = cell & 63;
    union { u16 s[8]; uint4 v; } tmp;
#pragma unroll
    for (int i = 0; i < 8; ++i) tmp.s[i] = f2bf(t[(kblk * 8 + i) * 65 + m]);
    *(uint4*)&X4[((size_t)(k0 / 8 + kblk) * 4096 + m0 + m) * 8] = tmp.v;
  }
}

// ---------------------------------------------------------------------------
// W4[kblk][n][8] bf16, k in [0,4096) rows [xr;xi;hr;hi]-weights.
// Packed col n = half*4096 + jhi*64 + g*16 + jlo  (j = jhi*16+jlo).
//   half=0 (zr): rows kq 0..3 -> Kr, Ki, Rr, Ri
//   half=1 (zi): rows kq 0..3 -> -Ki, Kr, -Ri, Rr
// ---------------------------------------------------------------------------
__global__ __launch_bounds__(256) void build_w_k(
    const float* __restrict__ Kr, const float* __restrict__ Ki,
    const float* __restrict__ Rr, const float* __restrict__ Ri,
    u16* __restrict__ W4) {
  __shared__ float t[4 * 1032];  // [g][k(64)][jlo(16)], per-g pitch 1032
  const int tid = threadIdx.x;
  const int tx = tid & 15, ty = tid >> 4;
  const int yb = blockIdx.y;           // [0,128): half(1) x jhi(64)
  const int hh = yb >> 6, jhi = yb & 63;
  const int k0 = blockIdx.x * 64;      // [0,4096)
  const int kq = k0 >> 10;
  const int krow = k0 & 1023;
  const int jbase = jhi * 16;
  const float* sA;
  float sg = 1.0f;
  if (hh == 0) {
    sA = (kq == 0) ? Kr : (kq == 1) ? Ki : (kq == 2) ? Rr : Ri;
  } else {
    sA = (kq == 0) ? Ki : (kq == 1) ? Kr : (kq == 2) ? Ri : Rr;
    if ((kq & 1) == 0) sg = -1.0f;
  }
#pragma unroll
  for (int g = 0; g < 4; ++g) {
    const int cs = g * 1024 + jbase + tx;
#pragma unroll
    for (int rr = 0; rr < 4; ++rr) {
      const int k = rr * 16 + ty;
      t[g * 1032 + k * 16 + tx] = sg * sA[(size_t)(krow + k) * 4096 + cs];
    }
  }
  __syncthreads();
#pragma unroll
  for (int rep = 0; rep < 2; ++rep) {
    const int cell = rep * 256 + tid;       // 512 cells: kblk(8) x n(64)
    const int kblk = cell >> 6, n = cell & 63;
    const int g = n >> 4, jlo = n & 15;
    union { u16 s[8]; uint4 v; } tmp;
#pragma unroll
    for (int i = 0; i < 8; ++i)
      tmp.s[i] = f2bf(t[g * 1032 + (kblk * 8 + i) * 16 + jlo]);
    *(uint4*)&W4[((size_t)(k0 / 8 + kblk) * 8192 + (size_t)hh * 4096 +
                  (size_t)jhi * 64 + n) * 8] = tmp.v;
  }
}

// ---------------------------------------------------------------------------
// Plain 4-product GEMM (M=4096, K=4096, Npacked=8192) + fused CLSTM epilogue.
// Canonical 256^2 / BK=64 / 8-wave (2Mx4N, per-wave 128x64, acc 128 f32) /
// 4-quadrant-phase schedule (m201-class):
//   phase = { 12 ds_read_b128 ; 2 global_load_lds ; [p3: counted vmcnt(4)] ;
//             s_barrier ; lgkmcnt(0) ; setprio(1) 16 MFMA setprio(0) ;
//             s_barrier }        -- NO sched_barrier (m141/R1 lesson)
// LDS = ring-9 x 16 KiB regions (144 KiB). K-tile kt = regions 4kt..4kt+3
// (A rows 0-127, A rows 128-255, B cols 0-127, B cols 128-255), slot = g%9.
// Stage lead L=6 regions (1.5 K-tiles): phase p of iter kt stages region
// g = 4kt+p+6 into slot g%9 (last reader >= 3 phase-barriers upstream).
// Ledger: vmcnt(4) at phase 3 leaves exactly 2 regions (4 loads) in flight;
// never drains to 0 mid-loop (T4).  T1 swizzle: mb = wg>>5 (A 2 panels/XCD,
// L2-resident), nb = wg&31 (B streamed from L3).
// ---------------------------------------------------------------------------
#define NKT 64

#define PHASE(P, QM, QN)                                                    \
  {                                                                         \
    bf16x8 af[4][2], bfr[2][2];                                             \
    _Pragma("unroll")                                                       \
    for (int ks = 0; ks < 2; ++ks) {                                        \
      _Pragma("unroll")                                                     \
      for (int mf = 0; mf < 4; ++mf)                                        \
        af[mf][ks] = *(const bf16x8*)&LA[abase + ks * 4096 + (QM) * 512 + mf * 128]; \
      _Pragma("unroll")                                                     \
      for (int nf = 0; nf < 2; ++nf)                                        \
        bfr[nf][ks] = *(const bf16x8*)&LB[bbase + ks * 4096 + (QN) * 256 + nf * 128]; \
    }                                                                       \
    if (gg < 256) { stageg(gg, ss); ++gg; ++ss; if (ss == 9) ss = 0; }      \
    if ((P) == 3) {                                                         \
      if (kt < NKT - 1) asm volatile("s_waitcnt vmcnt(4)" ::: "memory");    \
      else              asm volatile("s_waitcnt vmcnt(0)" ::: "memory");    \
    }                                                                       \
    __builtin_amdgcn_s_barrier();                                           \
    asm volatile("s_waitcnt lgkmcnt(0)" ::: "memory");                      \
    __builtin_amdgcn_s_setprio(1);                                          \
    _Pragma("unroll")                                                       \
    for (int ks = 0; ks < 2; ++ks)                                          \
      _Pragma("unroll")                                                     \
      for (int mf = 0; mf < 4; ++mf)                                        \
        _Pragma("unroll")                                                   \
        for (int nf = 0; nf < 2; ++nf)                                      \
          acc[(QM) * 4 + mf][(QN) * 2 + nf] =                               \
              __builtin_amdgcn_mfma_f32_16x16x32_bf16(                      \
                  af[mf][ks], bfr[nf][ks], acc[(QM) * 4 + mf][(QN) * 2 + nf], 0, 0, 0); \
    __builtin_amdgcn_s_setprio(0);                                          \
    __builtin_amdgcn_s_barrier();                                           \
  }

__global__ __launch_bounds__(512, 2) void clstm_gemm_k(
    const u16* __restrict__ X4, const u16* __restrict__ W4,
    const float* __restrict__ cprev, const float* __restrict__ rb,
    const float* __restrict__ ib, float* __restrict__ out) {
  __shared__ __align__(16) u16 lds[9][8192];  // 9 regions x 16 KiB = 144 KiB
  const int tid = threadIdx.x;
  const int lane = tid & 63, wave = tid >> 6;
  const int wr = wave >> 2, wc = wave & 3;  // 2M x 4N wave grid
  const int orig = blockIdx.x;
  const int wg = (orig & 7) * 64 + (orig >> 3);  // T1 (512 % 8 == 0)
  const int mb = wg >> 5, nb = wg & 31;  // A L2-resident (2/XCD), B streamed
  const int m0 = mb * 256, n0 = nb * 256;
  const u16* L = &lds[0][0];

  f32x4 acc[8][4] = {};  // [mf8][nf4] : rows 128 x cols 64 per wave

  // stage region g (global region index) into ring slot: 2 chunks per wave
  auto stageg = [&](int g, int slot) {
    const int ktile = g >> 2, r = g & 3;
    if (r < 2) {  // A rows r*128 .. +128, layout [kblk=wave][m(128)][8]
      const u16* s = X4 + ((size_t)(ktile * 8 + wave) * 4096 + m0 + r * 128 + lane) * 8;
      __builtin_amdgcn_global_load_lds((GAS*)s, (LAS*)&lds[slot][(wave * 128) * 8], 16, 0, 0);
      __builtin_amdgcn_global_load_lds((GAS*)(s + 512), (LAS*)&lds[slot][(wave * 128 + 64) * 8], 16, 0, 0);
    } else {      // B cols (r-2)*128 .. +128
      const u16* s = W4 + ((size_t)(ktile * 8 + wave) * 8192 + n0 + (r - 2) * 128 + lane) * 8;
      __builtin_amdgcn_global_load_lds((GAS*)s, (LAS*)&lds[slot][(wave * 128) * 8], 16, 0, 0);
      __builtin_amdgcn_global_load_lds((GAS*)(s + 512), (LAS*)&lds[slot][(wave * 128 + 64) * 8], 16, 0, 0);
    }
  };

  const int hi = lane >> 4, lo = lane & 15;
  const int abase = hi * 1024 + lo * 8;                    // + ks*4096 + qm*512 + mf*128
  const int bbase = hi * 1024 + (wc & 1) * 512 + lo * 8;   // + ks*4096 + qn*256 + nf*128

  // ---- prologue: regions 0..5 (K-tile 0 resident, K-tile 1 half-staged) ----
  for (int g = 0; g < 6; ++g) stageg(g, g);
  asm volatile("s_waitcnt vmcnt(4)" ::: "memory");  // regions 0..3 landed
  __builtin_amdgcn_s_barrier();

  int gg = 6, ss = 6, rbs = 0;
  for (int kt = 0; kt < NKT; ++kt) {
    int sA = rbs + wr;             if (sA >= 9) sA -= 9;
    int sB = rbs + 2 + (wc >> 1);  if (sB >= 9) sB -= 9;
    const u16* LA = L + sA * 8192;
    const u16* LB = L + sB * 8192;
    PHASE(0, 0, 0)
    PHASE(1, 0, 1)
    PHASE(2, 1, 0)
    PHASE(3, 1, 1)
    rbs += 4; if (rbs >= 9) rbs -= 9;
  }

  // ---- fused CLSTM epilogue (half = zr/zi selected by nb) ----
  const int half = nb >> 4;
  const int j = ((nb & 15) * 4 + wc) * 16 + lo;   // column in [0,1024)
  const float* bias = half ? ib : rb;
  float bs[4];
#pragma unroll
  for (int g = 0; g < 4; ++g) bs[g] = bias[g * 1024 + j];
#pragma unroll
  for (int mf8 = 0; mf8 < 8; ++mf8) {
    const int rowb = m0 + wr * 128 + mf8 * 16 + hi * 4;
#pragma unroll
    for (int r = 0; r < 4; ++r) {
      const size_t row = (size_t)(rowb + r);
      const float z0 = acc[mf8][0][r] + bs[0];
      const float z1 = acc[mf8][1][r] + bs[1];
      const float z2 = acc[mf8][2][r] + bs[2];
      const float z3 = acc[mf8][3][r] + bs[3];
      const float ig = fminf(fmaxf(0.2f * z0 + 0.5f, 0.0f), 1.0f);
      const float fg = fminf(fmaxf(0.2f * z1 + 0.5f, 0.0f), 1.0f);
      const float og = fminf(fmaxf(0.2f * z3 + 0.5f, 0.0f), 1.0f);
      const float cp = cprev[row * 2048 + half * 1024 + j];
      const float cn = fg * cp + ig * tanhf(z2);
      const float hn = og * tanhf(cn);
      out[row * 2048 + half * 1024 + j] = hn;
      out[(size_t)8388608 + row * 2048 + half * 1024 + j] = cn;
    }
  }
}

extern "C" void kernel_launch(void* const* d_in, const int* in_sizes, int n_in,
                              void* d_out, int out_size, void* d_ws, size_t ws_size,
                              hipStream_t stream) {
  const float* inputs = (const float*)d_in[0];
  const float* h_tm1  = (const float*)d_in[1];
  const float* c_tm1  = (const float*)d_in[2];
  const float* Kr     = (const float*)d_in[3];
  const float* Ki     = (const float*)d_in[4];
  const float* Rr     = (const float*)d_in[5];
  const float* Ri     = (const float*)d_in[6];
  const float* rb     = (const float*)d_in[7];
  const float* ib     = (const float*)d_in[8];
  float* out = (float*)d_out;

  u16* X4 = (u16*)d_ws;                       // 512*4096*8 u16 = 32 MiB
  u16* W4 = X4 + (size_t)512 * 4096 * 8;      // 512*8192*8 u16 = 64 MiB

  build_x_k<<<dim3(64, 64), 256, 0, stream>>>(inputs, h_tm1, X4);
  build_w_k<<<dim3(64, 128), 256, 0, stream>>>(Kr, Ki, Rr, Ri, W4);
  clstm_gemm_k<<<dim3(512, 1), 512, 0, stream>>>(X4, W4, c_tm1, rb, ib, out);
}

// Round 4
// 311.582 us; speedup vs baseline: 1.2526x; 1.1846x over previous
//
#include <hip/hip_runtime.h>

typedef unsigned short u16;
typedef unsigned int   u32;

typedef __bf16 bf16x8 __attribute__((ext_vector_type(8)));
typedef float  f32x4  __attribute__((ext_vector_type(4)));

typedef const __attribute__((address_space(1))) u32 GAS;
typedef __attribute__((address_space(3))) u32 LAS;

__device__ __forceinline__ u16 f2bf(float f) {
  u32 u = __builtin_bit_cast(u32, f);
  return (u16)((u + 0x7FFFu + ((u >> 16) & 1u)) >> 16);
}

// ---------------------------------------------------------------------------
// X4[kblk][m][8] bf16, k in [0,4096): [xr | xi | hr | hi] (1024 each)
// ---------------------------------------------------------------------------
__global__ __launch_bounds__(256) void build_x_k(
    const float* __restrict__ inp, const float* __restrict__ h,
    u16* __restrict__ X4) {
  __shared__ float t[64 * 65];  // t[k][m], pitch 65
  const int tid = threadIdx.x;
  const int tx = tid & 15, ty = tid >> 4;
  const int m0 = blockIdx.y * 64, k0 = blockIdx.x * 64;
  const int sel = k0 >> 10;          // 0:xr 1:xi 2:hr 3:hi
  const int kc = k0 & 1023;
  const float* s1 = (sel < 2) ? inp : h;
  const int c1 = (sel & 1) * 1024 + kc;
#pragma unroll
  for (int rr = 0; rr < 4; ++rr) {
    const int m = rr * 16 + ty;
    float4 v = *(const float4*)&s1[(size_t)(m0 + m) * 2048 + c1 + tx * 4];
    t[(tx * 4 + 0) * 65 + m] = v.x;
    t[(tx * 4 + 1) * 65 + m] = v.y;
    t[(tx * 4 + 2) * 65 + m] = v.z;
    t[(tx * 4 + 3) * 65 + m] = v.w;
  }
  __syncthreads();
#pragma unroll
  for (int rep = 0; rep < 2; ++rep) {
    const int cell = rep * 256 + tid;       // 512 cells: kblk(8) x m(64)
    const int kblk = cell >> 6, m = cell & 63;
    union { u16 s[8]; uint4 v; } tmp;
#pragma unroll
    for (int i = 0; i < 8; ++i) tmp.s[i] = f2bf(t[(kblk * 8 + i) * 65 + m]);
    *(uint4*)&X4[((size_t)(k0 / 8 + kblk) * 4096 + m0 + m) * 8] = tmp.v;
  }
}

// ---------------------------------------------------------------------------
// W4[kblk][n][8] bf16, k in [0,4096) rows [xr;xi;hr;hi]-weights.
// Packed col n = half*4096 + jhi*64 + g*16 + jlo  (j = jhi*16+jlo).
//   half=0 (zr): rows kq 0..3 -> Kr, Ki, Rr, Ri
//   half=1 (zi): rows kq 0..3 -> -Ki, Kr, -Ri, Rr
// ---------------------------------------------------------------------------
__global__ __launch_bounds__(256) void build_w_k(
    const float* __restrict__ Kr, const float* __restrict__ Ki,
    const float* __restrict__ Rr, const float* __restrict__ Ri,
    u16* __restrict__ W4) {
  __shared__ float t[4 * 1032];  // [g][k(64)][jlo(16)], per-g pitch 1032
  const int tid = threadIdx.x;
  const int tx = tid & 15, ty = tid >> 4;
  const int yb = blockIdx.y;           // [0,128): half(1) x jhi(64)
  const int hh = yb >> 6, jhi = yb & 63;
  const int k0 = blockIdx.x * 64;      // [0,4096)
  const int kq = k0 >> 10;
  const int krow = k0 & 1023;
  const int jbase = jhi * 16;
  const float* sA;
  float sg = 1.0f;
  if (hh == 0) {
    sA = (kq == 0) ? Kr : (kq == 1) ? Ki : (kq == 2) ? Rr : Ri;
  } else {
    sA = (kq == 0) ? Ki : (kq == 1) ? Kr : (kq == 2) ? Ri : Rr;
    if ((kq & 1) == 0) sg = -1.0f;
  }
#pragma unroll
  for (int g = 0; g < 4; ++g) {
    const int cs = g * 1024 + jbase + tx;
#pragma unroll
    for (int rr = 0; rr < 4; ++rr) {
      const int k = rr * 16 + ty;
      t[g * 1032 + k * 16 + tx] = sg * sA[(size_t)(krow + k) * 4096 + cs];
    }
  }
  __syncthreads();
#pragma unroll
  for (int rep = 0; rep < 2; ++rep) {
    const int cell = rep * 256 + tid;       // 512 cells: kblk(8) x n(64)
    const int kblk = cell >> 6, n = cell & 63;
    const int g = n >> 4, jlo = n & 15;
    union { u16 s[8]; uint4 v; } tmp;
#pragma unroll
    for (int i = 0; i < 8; ++i)
      tmp.s[i] = f2bf(t[g * 1032 + (kblk * 8 + i) * 16 + jlo]);
    *(uint4*)&W4[((size_t)(k0 / 8 + kblk) * 8192 + (size_t)hh * 4096 +
                  (size_t)jhi * 64 + n) * 8] = tmp.v;
  }
}

// ---------------------------------------------------------------------------
// Plain 4-product GEMM (M=4096, K=4096, Npacked=8192) + fused CLSTM epilogue.
// R4 = R3 phases + R2-proven sync skeleton:
//   Region g: 4kt+{0,1,2,3} = A-lo, A-hi, B-lo, B-hi of K-tile kt (16 KiB ea).
//   Ring-10 slots (160 KiB LDS), slot = g % 10.
//   Phases per kt: (ks0,qm0)[readB ks0], (ks0,qm1), (ks1,qm0)[readB ks1],
//   (ks1,qm1); B frags held in regs across the qm=1 phase ->
//   24 ds_read_b128/wave/K-tile (minimal).
//   Stages: p0/p1 -> B(kt+1) lo/hi (g=4kt+6,7); p2/p3 -> A(kt+2) lo/hi
//   (g=4kt+8,9).  Each stage targets the slot of a region of K-tile kt-1
//   whose last reader is >= 3 trailing barriers upstream (WAR-safe by
//   construction; fixes R2's latent p3 race).
//   Counted wait at p3 BEFORE its first barrier (R2-proven placement —
//   guarantee established before any kt+1 read is issued; fixes R3's race):
//   vmcnt(4) leaves exactly A(kt+2)'s 2 regions in flight; vmcnt(0) at
//   kt=NKT-2 (A(kt+2) not issued there); no wait at kt=NKT-1.
// T1 swizzle: mb = wg>>5 (A 2 panels/XCD, L2-resident), nb = wg&31.
// ---------------------------------------------------------------------------
#define NKT 64

__global__ __launch_bounds__(512, 2) void clstm_gemm_k(
    const u16* __restrict__ X4, const u16* __restrict__ W4,
    const float* __restrict__ cprev, const float* __restrict__ rb,
    const float* __restrict__ ib, float* __restrict__ out) {
  __shared__ __align__(16) u16 lds[10][8192];  // 10 regions x 16 KiB = 160 KiB
  const int tid = threadIdx.x;
  const int lane = tid & 63, wave = tid >> 6;
  const int wr = wave >> 2, wc = wave & 3;  // 2M x 4N wave grid
  const int orig = blockIdx.x;
  const int wg = (orig & 7) * 64 + (orig >> 3);  // T1 (512 % 8 == 0)
  const int mb = wg >> 5, nb = wg & 31;  // A L2-resident (2/XCD), B streamed
  const int m0 = mb * 256, n0 = nb * 256;
  const u16* L = &lds[0][0];

  f32x4 acc[8][4] = {};  // [mf8][nf4] : rows 128 x cols 64 per wave

  auto stageA = [&](int ktile, int hf, int slot) {
    const u16* s = X4 + ((size_t)(ktile * 8 + wave) * 4096 + m0 + hf * 128 + lane) * 8;
    __builtin_amdgcn_global_load_lds((GAS*)s, (LAS*)&lds[slot][(wave * 128) * 8], 16, 0, 0);
    __builtin_amdgcn_global_load_lds((GAS*)(s + 512), (LAS*)&lds[slot][(wave * 128 + 64) * 8], 16, 0, 0);
  };
  auto stageB = [&](int ktile, int hf, int slot) {
    const u16* s = W4 + ((size_t)(ktile * 8 + wave) * 8192 + n0 + hf * 128 + lane) * 8;
    __builtin_amdgcn_global_load_lds((GAS*)s, (LAS*)&lds[slot][(wave * 128) * 8], 16, 0, 0);
    __builtin_amdgcn_global_load_lds((GAS*)(s + 512), (LAS*)&lds[slot][(wave * 128 + 64) * 8], 16, 0, 0);
  };

  const int hi = lane >> 4, lo = lane & 15;
  const int abase = hi * 1024 + lo * 8;                    // + ks*4096 + qm*512 + mf*128
  const int bbase = hi * 1024 + (wc & 1) * 512 + lo * 8;   // + ks*4096 + n*128

  // ---- prologue: regions 0..5 (A0, B0, A1) into slots 0..5 ----
  stageA(0, 0, 0); stageA(0, 1, 1);
  stageB(0, 0, 2); stageB(0, 1, 3);
  stageA(1, 0, 4); stageA(1, 1, 5);
  asm volatile("s_waitcnt vmcnt(4)" ::: "memory");  // regions 0..3 landed
  __builtin_amdgcn_s_barrier();

  int rbs = 0, ss = 6;
  for (int kt = 0; kt < NKT; ++kt) {
    int sA = rbs + wr;             if (sA >= 10) sA -= 10;
    int sB = rbs + 2 + (wc >> 1);  if (sB >= 10) sB -= 10;
    const u16* LA = L + sA * 8192;
    const u16* LB = L + sB * 8192;
    bf16x8 av[4], bq[4];

    // ---- phase 0: ks=0, qm=0 (+ B[ks0] into held regs) ----
#pragma unroll
    for (int mf = 0; mf < 4; ++mf)
      av[mf] = *(const bf16x8*)&LA[abase + mf * 128];
#pragma unroll
    for (int n = 0; n < 4; ++n)
      bq[n] = *(const bf16x8*)&LB[bbase + n * 128];
    if (kt + 1 < NKT) { stageB(kt + 1, 0, ss); ++ss; if (ss == 10) ss = 0; }
    __builtin_amdgcn_s_barrier();
    asm volatile("s_waitcnt lgkmcnt(0)" ::: "memory");
    __builtin_amdgcn_s_setprio(1);
#pragma unroll
    for (int mf = 0; mf < 4; ++mf)
#pragma unroll
      for (int n = 0; n < 4; ++n)
        acc[mf][n] = __builtin_amdgcn_mfma_f32_16x16x32_bf16(av[mf], bq[n], acc[mf][n], 0, 0, 0);
    __builtin_amdgcn_s_setprio(0);
    __builtin_amdgcn_s_barrier();

    // ---- phase 1: ks=0, qm=1 (reuse bq) ----
#pragma unroll
    for (int mf = 0; mf < 4; ++mf)
      av[mf] = *(const bf16x8*)&LA[abase + 512 + mf * 128];
    if (kt + 1 < NKT) { stageB(kt + 1, 1, ss); ++ss; if (ss == 10) ss = 0; }
    __builtin_amdgcn_s_barrier();
    asm volatile("s_waitcnt lgkmcnt(0)" ::: "memory");
    __builtin_amdgcn_s_setprio(1);
#pragma unroll
    for (int mf = 0; mf < 4; ++mf)
#pragma unroll
      for (int n = 0; n < 4; ++n)
        acc[4 + mf][n] = __builtin_amdgcn_mfma_f32_16x16x32_bf16(av[mf], bq[n], acc[4 + mf][n], 0, 0, 0);
    __builtin_amdgcn_s_setprio(0);
    __builtin_amdgcn_s_barrier();

    // ---- phase 2: ks=1, qm=0 (+ B[ks1] into held regs) ----
#pragma unroll
    for (int mf = 0; mf < 4; ++mf)
      av[mf] = *(const bf16x8*)&LA[abase + 4096 + mf * 128];
#pragma unroll
    for (int n = 0; n < 4; ++n)
      bq[n] = *(const bf16x8*)&LB[bbase + 4096 + n * 128];
    if (kt + 2 < NKT) { stageA(kt + 2, 0, ss); ++ss; if (ss == 10) ss = 0; }
    __builtin_amdgcn_s_barrier();
    asm volatile("s_waitcnt lgkmcnt(0)" ::: "memory");
    __builtin_amdgcn_s_setprio(1);
#pragma unroll
    for (int mf = 0; mf < 4; ++mf)
#pragma unroll
      for (int n = 0; n < 4; ++n)
        acc[mf][n] = __builtin_amdgcn_mfma_f32_16x16x32_bf16(av[mf], bq[n], acc[mf][n], 0, 0, 0);
    __builtin_amdgcn_s_setprio(0);
    __builtin_amdgcn_s_barrier();

    // ---- phase 3: ks=1, qm=1 (reuse bq) + counted drain for kt+1 ----
#pragma unroll
    for (int mf = 0; mf < 4; ++mf)
      av[mf] = *(const bf16x8*)&LA[abase + 4096 + 512 + mf * 128];
    if (kt + 2 < NKT) { stageA(kt + 2, 1, ss); ++ss; if (ss == 10) ss = 0; }
    if (kt < NKT - 2)       asm volatile("s_waitcnt vmcnt(4)" ::: "memory");
    else if (kt == NKT - 2) asm volatile("s_waitcnt vmcnt(0)" ::: "memory");
    __builtin_amdgcn_s_barrier();
    asm volatile("s_waitcnt lgkmcnt(0)" ::: "memory");
    __builtin_amdgcn_s_setprio(1);
#pragma unroll
    for (int mf = 0; mf < 4; ++mf)
#pragma unroll
      for (int n = 0; n < 4; ++n)
        acc[4 + mf][n] = __builtin_amdgcn_mfma_f32_16x16x32_bf16(av[mf], bq[n], acc[4 + mf][n], 0, 0, 0);
    __builtin_amdgcn_s_setprio(0);
    __builtin_amdgcn_s_barrier();

    rbs += 4; if (rbs >= 10) rbs -= 10;
  }

  // ---- fused CLSTM epilogue (half = zr/zi selected by nb) ----
  const int half = nb >> 4;
  const int j = ((nb & 15) * 4 + wc) * 16 + lo;   // column in [0,1024)
  const float* bias = half ? ib : rb;
  float bs[4];
#pragma unroll
  for (int g = 0; g < 4; ++g) bs[g] = bias[g * 1024 + j];
#pragma unroll
  for (int mf8 = 0; mf8 < 8; ++mf8) {
    const int rowb = m0 + wr * 128 + mf8 * 16 + hi * 4;
#pragma unroll
    for (int r = 0; r < 4; ++r) {
      const size_t row = (size_t)(rowb + r);
      const float z0 = acc[mf8][0][r] + bs[0];
      const float z1 = acc[mf8][1][r] + bs[1];
      const float z2 = acc[mf8][2][r] + bs[2];
      const float z3 = acc[mf8][3][r] + bs[3];
      const float ig = fminf(fmaxf(0.2f * z0 + 0.5f, 0.0f), 1.0f);
      const float fg = fminf(fmaxf(0.2f * z1 + 0.5f, 0.0f), 1.0f);
      const float og = fminf(fmaxf(0.2f * z3 + 0.5f, 0.0f), 1.0f);
      const float cp = cprev[row * 2048 + half * 1024 + j];
      const float cn = fg * cp + ig * tanhf(z2);
      const float hn = og * tanhf(cn);
      out[row * 2048 + half * 1024 + j] = hn;
      out[(size_t)8388608 + row * 2048 + half * 1024 + j] = cn;
    }
  }
}

extern "C" void kernel_launch(void* const* d_in, const int* in_sizes, int n_in,
                              void* d_out, int out_size, void* d_ws, size_t ws_size,
                              hipStream_t stream) {
  const float* inputs = (const float*)d_in[0];
  const float* h_tm1  = (const float*)d_in[1];
  const float* c_tm1  = (const float*)d_in[2];
  const float* Kr     = (const float*)d_in[3];
  const float* Ki     = (const float*)d_in[4];
  const float* Rr     = (const float*)d_in[5];
  const float* Ri     = (const float*)d_in[6];
  const float* rb     = (const float*)d_in[7];
  const float* ib     = (const float*)d_in[8];
  float* out = (float*)d_out;

  u16* X4 = (u16*)d_ws;                       // 512*4096*8 u16 = 32 MiB
  u16* W4 = X4 + (size_t)512 * 4096 * 8;      // 512*8192*8 u16 = 64 MiB

  build_x_k<<<dim3(64, 64), 256, 0, stream>>>(inputs, h_tm1, X4);
  build_w_k<<<dim3(64, 128), 256, 0, stream>>>(Kr, Ki, Rr, Ri, W4);
  clstm_gemm_k<<<dim3(512, 1), 512, 0, stream>>>(X4, W4, c_tm1, rb, ib, out);
}

// Round 5
// 306.966 us; speedup vs baseline: 1.2714x; 1.0150x over previous
//
#include <hip/hip_runtime.h>

typedef unsigned short u16;
typedef unsigned int   u32;

typedef __bf16 bf16x8 __attribute__((ext_vector_type(8)));
typedef float  f32x4  __attribute__((ext_vector_type(4)));

typedef const __attribute__((address_space(1))) u32 GAS;
typedef __attribute__((address_space(3))) u32 LAS;

__device__ __forceinline__ u16 f2bf(float f) {
  u32 u = __builtin_bit_cast(u32, f);
  return (u16)((u + 0x7FFFu + ((u >> 16) & 1u)) >> 16);
}

// ---------------------------------------------------------------------------
// X4[kblk][m][8] bf16, k in [0,4096): [xr | xi | hr | hi] (1024 each)
// ---------------------------------------------------------------------------
__global__ __launch_bounds__(256) void build_x_k(
    const float* __restrict__ inp, const float* __restrict__ h,
    u16* __restrict__ X4) {
  __shared__ float t[64 * 65];  // t[k][m], pitch 65
  const int tid = threadIdx.x;
  const int tx = tid & 15, ty = tid >> 4;
  const int m0 = blockIdx.y * 64, k0 = blockIdx.x * 64;
  const int sel = k0 >> 10;          // 0:xr 1:xi 2:hr 3:hi
  const int kc = k0 & 1023;
  const float* s1 = (sel < 2) ? inp : h;
  const int c1 = (sel & 1) * 1024 + kc;
#pragma unroll
  for (int rr = 0; rr < 4; ++rr) {
    const int m = rr * 16 + ty;
    float4 v = *(const float4*)&s1[(size_t)(m0 + m) * 2048 + c1 + tx * 4];
    t[(tx * 4 + 0) * 65 + m] = v.x;
    t[(tx * 4 + 1) * 65 + m] = v.y;
    t[(tx * 4 + 2) * 65 + m] = v.z;
    t[(tx * 4 + 3) * 65 + m] = v.w;
  }
  __syncthreads();
#pragma unroll
  for (int rep = 0; rep < 2; ++rep) {
    const int cell = rep * 256 + tid;       // 512 cells: kblk(8) x m(64)
    const int kblk = cell >> 6, m = cell & 63;
    union { u16 s[8]; uint4 v; } tmp;
#pragma unroll
    for (int i = 0; i < 8; ++i) tmp.s[i] = f2bf(t[(kblk * 8 + i) * 65 + m]);
    *(uint4*)&X4[((size_t)(k0 / 8 + kblk) * 4096 + m0 + m) * 8] = tmp.v;
  }
}

// ---------------------------------------------------------------------------
// W4[kblk][n][8] bf16, k in [0,4096) rows [xr;xi;hr;hi]-weights.
// Packed col n = half*4096 + jhi*64 + g*16 + jlo  (j = jhi*16+jlo).
//   half=0 (zr): rows kq 0..3 -> Kr, Ki, Rr, Ri
//   half=1 (zi): rows kq 0..3 -> -Ki, Kr, -Ri, Rr
// ---------------------------------------------------------------------------
__global__ __launch_bounds__(256) void build_w_k(
    const float* __restrict__ Kr, const float* __restrict__ Ki,
    const float* __restrict__ Rr, const float* __restrict__ Ri,
    u16* __restrict__ W4) {
  __shared__ float t[4 * 1032];  // [g][k(64)][jlo(16)], per-g pitch 1032
  const int tid = threadIdx.x;
  const int tx = tid & 15, ty = tid >> 4;
  const int yb = blockIdx.y;           // [0,128): half(1) x jhi(64)
  const int hh = yb >> 6, jhi = yb & 63;
  const int k0 = blockIdx.x * 64;      // [0,4096)
  const int kq = k0 >> 10;
  const int krow = k0 & 1023;
  const int jbase = jhi * 16;
  const float* sA;
  float sg = 1.0f;
  if (hh == 0) {
    sA = (kq == 0) ? Kr : (kq == 1) ? Ki : (kq == 2) ? Rr : Ri;
  } else {
    sA = (kq == 0) ? Ki : (kq == 1) ? Kr : (kq == 2) ? Ri : Rr;
    if ((kq & 1) == 0) sg = -1.0f;
  }
#pragma unroll
  for (int g = 0; g < 4; ++g) {
    const int cs = g * 1024 + jbase + tx;
#pragma unroll
    for (int rr = 0; rr < 4; ++rr) {
      const int k = rr * 16 + ty;
      t[g * 1032 + k * 16 + tx] = sg * sA[(size_t)(krow + k) * 4096 + cs];
    }
  }
  __syncthreads();
#pragma unroll
  for (int rep = 0; rep < 2; ++rep) {
    const int cell = rep * 256 + tid;       // 512 cells: kblk(8) x n(64)
    const int kblk = cell >> 6, n = cell & 63;
    const int g = n >> 4, jlo = n & 15;
    union { u16 s[8]; uint4 v; } tmp;
#pragma unroll
    for (int i = 0; i < 8; ++i)
      tmp.s[i] = f2bf(t[g * 1032 + (kblk * 8 + i) * 16 + jlo]);
    *(uint4*)&W4[((size_t)(k0 / 8 + kblk) * 8192 + (size_t)hh * 4096 +
                  (size_t)jhi * 64 + n) * 8] = tmp.v;
  }
}

// ---------------------------------------------------------------------------
// Plain 4-product GEMM (M=4096, K=4096, Npacked=8192) + fused CLSTM epilogue.
// R5: register-double-buffered frags, ONE barrier per phase.
//   Phase p: { barrier ; stage (post-barrier, WAR-provable) ; issue ds_reads
//   for phase p+1 into spare bank ; counted lgkmcnt (drains only previous
//   batch) ; 16 MFMA on current bank }.
//   MFMA(p) consumes regs loaded in p-1 while the LDS unit streams reads for
//   p+1 -> LDS-read time (2313 cyc/CU/kt) hides under MFMA (2483 cyc/SIMD/kt).
//   Banks: avA/avB alternate every phase; bqA (ks0, loaded at prev p3) used
//   p0/p1, bqB (ks1, loaded p1) used p2/p3.  Counted lgkm = just-issued batch
//   size: p0:4, p1:8, p2:4, p3:8.
// Ring-10 slots (160 KiB), region g = 4kt+{0,1,2,3} = A-lo,A-hi,B-lo,B-hi.
// Stages: p0/p1 -> B(kt+1) lo/hi (g=4kt+6,7); p2/p3 -> A(kt+2) lo/hi
// (g=4kt+8,9).  All stages post-barrier: victim's last reader finished its
// reads before its own counted wait one phase earlier, which precedes the
// barrier the stager just passed -> WAR proven for all 4 victims.
// vmcnt(2) at p3 pre-barrier (A(kt+2)lo alone in flight; +2 post-barrier ->
// never 0 mid-loop); vmcnt(0) at kt=NKT-2; none at kt=NKT-1.
// T1 swizzle: mb = wg>>5 (A 2 panels/XCD, L2-resident), nb = wg&31.
// ---------------------------------------------------------------------------
#define NKT 64

#define MFMA16(AV, BQ, Q)                                                   \
  __builtin_amdgcn_s_setprio(1);                                            \
  _Pragma("unroll")                                                         \
  for (int mf = 0; mf < 4; ++mf)                                            \
    _Pragma("unroll")                                                       \
    for (int n = 0; n < 4; ++n)                                             \
      acc[(Q) * 4 + mf][n] = __builtin_amdgcn_mfma_f32_16x16x32_bf16(       \
          AV[mf], BQ[n], acc[(Q) * 4 + mf][n], 0, 0, 0);                    \
  __builtin_amdgcn_s_setprio(0);

__global__ __launch_bounds__(512, 2) void clstm_gemm_k(
    const u16* __restrict__ X4, const u16* __restrict__ W4,
    const float* __restrict__ cprev, const float* __restrict__ rb,
    const float* __restrict__ ib, float* __restrict__ out) {
  __shared__ __align__(16) u16 lds[10][8192];  // 10 regions x 16 KiB = 160 KiB
  const int tid = threadIdx.x;
  const int lane = tid & 63, wave = tid >> 6;
  const int wr = wave >> 2, wc = wave & 3;  // 2M x 4N wave grid
  const int orig = blockIdx.x;
  const int wg = (orig & 7) * 64 + (orig >> 3);  // T1 (512 % 8 == 0)
  const int mb = wg >> 5, nb = wg & 31;  // A L2-resident (2/XCD), B streamed
  const int m0 = mb * 256, n0 = nb * 256;
  const u16* L = &lds[0][0];

  f32x4 acc[8][4] = {};  // [mf8][nf4] : rows 128 x cols 64 per wave

  auto stageA = [&](int ktile, int hf, int slot) {
    const u16* s = X4 + ((size_t)(ktile * 8 + wave) * 4096 + m0 + hf * 128 + lane) * 8;
    __builtin_amdgcn_global_load_lds((GAS*)s, (LAS*)&lds[slot][(wave * 128) * 8], 16, 0, 0);
    __builtin_amdgcn_global_load_lds((GAS*)(s + 512), (LAS*)&lds[slot][(wave * 128 + 64) * 8], 16, 0, 0);
  };
  auto stageB = [&](int ktile, int hf, int slot) {
    const u16* s = W4 + ((size_t)(ktile * 8 + wave) * 8192 + n0 + hf * 128 + lane) * 8;
    __builtin_amdgcn_global_load_lds((GAS*)s, (LAS*)&lds[slot][(wave * 128) * 8], 16, 0, 0);
    __builtin_amdgcn_global_load_lds((GAS*)(s + 512), (LAS*)&lds[slot][(wave * 128 + 64) * 8], 16, 0, 0);
  };

  const int hi = lane >> 4, lo = lane & 15;
  const int abase = hi * 1024 + lo * 8;                    // + qm*512 + ks*4096 + mf*128
  const int bbase = hi * 1024 + (wc & 1) * 512 + lo * 8;   // + ks*4096 + n*128

  // ---- prologue: regions 0..5 (A0, B0, A1) into slots 0..5 ----
  stageA(0, 0, 0); stageA(0, 1, 1);
  stageB(0, 0, 2); stageB(0, 1, 3);
  stageA(1, 0, 4); stageA(1, 1, 5);
  asm volatile("s_waitcnt vmcnt(4)" ::: "memory");  // regions 0..3 landed
  __builtin_amdgcn_s_barrier();

  bf16x8 avA[4], avB[4], bqA[4], bqB[4];
  {  // pre-load kt0 p0 frag bank
    const u16* LA = L + (size_t)(0 + wr) * 8192;
    const u16* LB = L + (size_t)(2 + (wc >> 1)) * 8192;
#pragma unroll
    for (int mf = 0; mf < 4; ++mf) avA[mf] = *(const bf16x8*)&LA[abase + mf * 128];
#pragma unroll
    for (int n = 0; n < 4; ++n)    bqA[n]  = *(const bf16x8*)&LB[bbase + n * 128];
  }

  int rbs = 0, ss = 6;
  for (int kt = 0; kt < NKT; ++kt) {
    int sA = rbs + wr;             if (sA >= 10) sA -= 10;
    int sB = rbs + 2 + (wc >> 1);  if (sB >= 10) sB -= 10;
    const u16* LA = L + (size_t)sA * 8192;
    const u16* LB = L + (size_t)sB * 8192;

    // ---- phase 0: MFMA(ks0,qm0) on avA,bqA; prefetch av(p1)->avB ----
    __builtin_amdgcn_s_barrier();
    if (kt + 1 < NKT) { stageB(kt + 1, 0, ss); ++ss; if (ss == 10) ss = 0; }
#pragma unroll
    for (int mf = 0; mf < 4; ++mf) avB[mf] = *(const bf16x8*)&LA[abase + 512 + mf * 128];
    asm volatile("s_waitcnt lgkmcnt(4)" ::: "memory");
    MFMA16(avA, bqA, 0)

    // ---- phase 1: MFMA(ks0,qm1) on avB,bqA; prefetch av(p2)->avA, bq(ks1)->bqB ----
    __builtin_amdgcn_s_barrier();
    if (kt + 1 < NKT) { stageB(kt + 1, 1, ss); ++ss; if (ss == 10) ss = 0; }
#pragma unroll
    for (int mf = 0; mf < 4; ++mf) avA[mf] = *(const bf16x8*)&LA[abase + 4096 + mf * 128];
#pragma unroll
    for (int n = 0; n < 4; ++n)    bqB[n]  = *(const bf16x8*)&LB[bbase + 4096 + n * 128];
    asm volatile("s_waitcnt lgkmcnt(8)" ::: "memory");
    MFMA16(avB, bqA, 1)

    // ---- phase 2: MFMA(ks1,qm0) on avA,bqB; prefetch av(p3)->avB ----
    __builtin_amdgcn_s_barrier();
    if (kt + 2 < NKT) { stageA(kt + 2, 0, ss); ++ss; if (ss == 10) ss = 0; }
#pragma unroll
    for (int mf = 0; mf < 4; ++mf) avB[mf] = *(const bf16x8*)&LA[abase + 4096 + 512 + mf * 128];
    asm volatile("s_waitcnt lgkmcnt(4)" ::: "memory");
    MFMA16(avA, bqB, 0)

    // ---- phase 3: vmcnt; MFMA(ks1,qm1) on avB,bqB; prefetch kt+1 p0 bank ----
    if (kt < NKT - 2)       asm volatile("s_waitcnt vmcnt(2)" ::: "memory");
    else if (kt == NKT - 2) asm volatile("s_waitcnt vmcnt(0)" ::: "memory");
    __builtin_amdgcn_s_barrier();
    if (kt + 2 < NKT) { stageA(kt + 2, 1, ss); ++ss; if (ss == 10) ss = 0; }
    if (kt + 1 < NKT) {
      int rbs2 = rbs + 4; if (rbs2 >= 10) rbs2 -= 10;
      int sA2 = rbs2 + wr;             if (sA2 >= 10) sA2 -= 10;
      int sB2 = rbs2 + 2 + (wc >> 1);  if (sB2 >= 10) sB2 -= 10;
      const u16* LA2 = L + (size_t)sA2 * 8192;
      const u16* LB2 = L + (size_t)sB2 * 8192;
#pragma unroll
      for (int mf = 0; mf < 4; ++mf) avA[mf] = *(const bf16x8*)&LA2[abase + mf * 128];
#pragma unroll
      for (int n = 0; n < 4; ++n)    bqA[n]  = *(const bf16x8*)&LB2[bbase + n * 128];
      asm volatile("s_waitcnt lgkmcnt(8)" ::: "memory");
    } else {
      asm volatile("s_waitcnt lgkmcnt(0)" ::: "memory");
    }
    MFMA16(avB, bqB, 1)

    rbs += 4; if (rbs >= 10) rbs -= 10;
  }

  // ---- fused CLSTM epilogue (half = zr/zi selected by nb) ----
  const int half = nb >> 4;
  const int j = ((nb & 15) * 4 + wc) * 16 + lo;   // column in [0,1024)
  const float* bias = half ? ib : rb;
  float bs[4];
#pragma unroll
  for (int g = 0; g < 4; ++g) bs[g] = bias[g * 1024 + j];
#pragma unroll
  for (int mf8 = 0; mf8 < 8; ++mf8) {
    const int rowb = m0 + wr * 128 + mf8 * 16 + hi * 4;
#pragma unroll
    for (int r = 0; r < 4; ++r) {
      const size_t row = (size_t)(rowb + r);
      const float z0 = acc[mf8][0][r] + bs[0];
      const float z1 = acc[mf8][1][r] + bs[1];
      const float z2 = acc[mf8][2][r] + bs[2];
      const float z3 = acc[mf8][3][r] + bs[3];
      const float ig = fminf(fmaxf(0.2f * z0 + 0.5f, 0.0f), 1.0f);
      const float fg = fminf(fmaxf(0.2f * z1 + 0.5f, 0.0f), 1.0f);
      const float og = fminf(fmaxf(0.2f * z3 + 0.5f, 0.0f), 1.0f);
      const float cp = cprev[row * 2048 + half * 1024 + j];
      const float cn = fg * cp + ig * tanhf(z2);
      const float hn = og * tanhf(cn);
      out[row * 2048 + half * 1024 + j] = hn;
      out[(size_t)8388608 + row * 2048 + half * 1024 + j] = cn;
    }
  }
}

extern "C" void kernel_launch(void* const* d_in, const int* in_sizes, int n_in,
                              void* d_out, int out_size, void* d_ws, size_t ws_size,
                              hipStream_t stream) {
  const float* inputs = (const float*)d_in[0];
  const float* h_tm1  = (const float*)d_in[1];
  const float* c_tm1  = (const float*)d_in[2];
  const float* Kr     = (const float*)d_in[3];
  const float* Ki     = (const float*)d_in[4];
  const float* Rr     = (const float*)d_in[5];
  const float* Ri     = (const float*)d_in[6];
  const float* rb     = (const float*)d_in[7];
  const float* ib     = (const float*)d_in[8];
  float* out = (float*)d_out;

  u16* X4 = (u16*)d_ws;                       // 512*4096*8 u16 = 32 MiB
  u16* W4 = X4 + (size_t)512 * 4096 * 8;      // 512*8192*8 u16 = 64 MiB

  build_x_k<<<dim3(64, 64), 256, 0, stream>>>(inputs, h_tm1, X4);
  build_w_k<<<dim3(64, 128), 256, 0, stream>>>(Kr, Ki, Rr, Ri, W4);
  clstm_gemm_k<<<dim3(512, 1), 512, 0, stream>>>(X4, W4, c_tm1, rb, ib, out);
}

// Round 6
// 284.085 us; speedup vs baseline: 1.3738x; 1.0805x over previous
//
#include <hip/hip_runtime.h>

typedef unsigned short u16;
typedef unsigned int   u32;

typedef __bf16 bf16x8 __attribute__((ext_vector_type(8)));
typedef float  f32x4  __attribute__((ext_vector_type(4)));

typedef const __attribute__((address_space(1))) u32 GAS;
typedef __attribute__((address_space(3))) u32 LAS;

__device__ __forceinline__ u16 f2bf(float f) {
  u32 u = __builtin_bit_cast(u32, f);
  return (u16)((u + 0x7FFFu + ((u >> 16) & 1u)) >> 16);
}

// ---------------------------------------------------------------------------
// X3[kblk][m][8] bf16, kblk = k/8, m in [0,4096), k in [0,6144):
//   seg0 [xr | hr], seg1 [xi | hi], seg2 [xr+xi | hr+hi]   (R0-proven)
// ---------------------------------------------------------------------------
__global__ __launch_bounds__(256) void build_x_k(
    const float* __restrict__ inp, const float* __restrict__ h,
    u16* __restrict__ X3) {
  __shared__ float t[64 * 65];  // t[k][m], pitch 65
  const int tid = threadIdx.x;
  const int tx = tid & 15, ty = tid >> 4;
  const int m0 = blockIdx.y * 64, k0 = blockIdx.x * 64;
  const int sel = k0 >> 10;          // uniform per block
  const int kc = k0 & 1023;
  const float* s1 = (sel == 0 || sel == 2 || sel == 4) ? inp : h;
  const int c1 = (sel == 2 || sel == 3) ? (1024 + kc) : kc;
  const bool pair = (sel >= 4);      // add column c1 + 1024 of same source
#pragma unroll
  for (int rr = 0; rr < 4; ++rr) {
    const int m = rr * 16 + ty;
    float4 v = *(const float4*)&s1[(size_t)(m0 + m) * 2048 + c1 + tx * 4];
    if (pair) {
      const float4 w = *(const float4*)&s1[(size_t)(m0 + m) * 2048 + c1 + 1024 + tx * 4];
      v.x += w.x; v.y += w.y; v.z += w.z; v.w += w.w;
    }
    t[(tx * 4 + 0) * 65 + m] = v.x;
    t[(tx * 4 + 1) * 65 + m] = v.y;
    t[(tx * 4 + 2) * 65 + m] = v.z;
    t[(tx * 4 + 3) * 65 + m] = v.w;
  }
  __syncthreads();
#pragma unroll
  for (int rep = 0; rep < 2; ++rep) {
    const int cell = rep * 256 + tid;       // 512 cells: kblk(8) x m(64)
    const int kblk = cell >> 6, m = cell & 63;
    union { u16 s[8]; uint4 v; } tmp;
#pragma unroll
    for (int i = 0; i < 8; ++i) tmp.s[i] = f2bf(t[(kblk * 8 + i) * 65 + m]);
    *(uint4*)&X3[((size_t)(k0 / 8 + kblk) * 4096 + m0 + m) * 8] = tmp.v;
  }
}

// ---------------------------------------------------------------------------
// W3[kblk][n][8] bf16, rows k in [0,6144): seg0 [Kr;Rr], seg1 [Ki;Ri],
// seg2 [Kr-Ki; Rr-Ri].  Cols n = (j>>4)*64 + g*16 + (j&15).   (R0-proven)
// ---------------------------------------------------------------------------
__global__ __launch_bounds__(256) void build_w_k(
    const float* __restrict__ Kr, const float* __restrict__ Ki,
    const float* __restrict__ Rr, const float* __restrict__ Ri,
    u16* __restrict__ W3) {
  __shared__ float t[4 * 1032];  // [g][k(64)][jlo(16)], per-g pitch 1032
  const int tid = threadIdx.x;
  const int tx = tid & 15, ty = tid >> 4;
  const int jhi = blockIdx.y;          // [0,64): 16-j group
  const int k0 = blockIdx.x * 64;      // [0,6144)
  const int sel = k0 >> 10;            // 0:Kr 1:Rr 2:Ki 3:Ri 4:Kr-Ki 5:Rr-Ri
  const int krow = k0 & 1023;
  const int jbase = jhi * 16;
  const float* sA = (sel == 0) ? Kr : (sel == 1) ? Rr : (sel == 2) ? Ki
                  : (sel == 3) ? Ri : (sel == 4) ? Kr : Rr;
  const float* sB = (sel == 4) ? Ki : (sel == 5) ? Ri : nullptr;
#pragma unroll
  for (int g = 0; g < 4; ++g) {
    const int cs = g * 1024 + jbase + tx;
#pragma unroll
    for (int rr = 0; rr < 4; ++rr) {
      const int k = rr * 16 + ty;
      float v = sA[(size_t)(krow + k) * 4096 + cs];
      if (sel >= 4) v -= sB[(size_t)(krow + k) * 4096 + cs];
      t[g * 1032 + k * 16 + tx] = v;
    }
  }
  __syncthreads();
#pragma unroll
  for (int rep = 0; rep < 2; ++rep) {
    const int cell = rep * 256 + tid;       // 512 cells: kblk(8) x n(64)
    const int kblk = cell >> 6, n = cell & 63;
    const int g = n >> 4, jlo = n & 15;
    union { u16 s[8]; uint4 v; } tmp;
#pragma unroll
    for (int i = 0; i < 8; ++i)
      tmp.s[i] = f2bf(t[g * 1032 + (kblk * 8 + i) * 16 + jlo]);
    *(uint4*)&W3[((size_t)(k0 / 8 + kblk) * 4096 + (size_t)jhi * 64 + n) * 8] = tmp.v;
  }
}

// ---------------------------------------------------------------------------
// Gauss 3-product GEMM (M=4096, Kg=6144, Npacked=4096) + fused CLSTM epilogue.
// R6 = R5's proven loop body on the Gauss work set (0.75x FLOP of R4/R5).
// BM=128, BN=256pc, BK=64; 8 waves 2Mx4N, per-wave 64x64, acc = 2 banks x 64.
// Regions (16 KiB each): kt -> {A(kt), Blo(kt), Bhi(kt)}; ring-10 (160 KiB),
// slot = (3kt + r) % 10; stage lead = 2 K-tiles (7 free regions).
// Phases per kt (R5 skeleton, 2 phases since per-wave tile is 64x64):
//  p0: barrier; stage A(kt+2),Blo(kt+2); ds_read ks1 frags (8); lgkm(8)
//      [drains prev preload]; 16 MFMA on ks0 bank.
//  p1: stage Bhi(kt+2); vmcnt(6) [12 outstanding: kt+1's 6 oldest drain,
//      kt+2's 6 stay; vmcnt(0) at kt=94, none at 95]; barrier; preload
//      kt+1 ks0 frags (8); lgkm(8); 16 MFMA on ks1 bank.
// WAR audit: stages at kt p0 hit slots of Bhi(kt-2) & A(kt-1); kt p1 hits
// Blo(kt-1).  Each victim's last ds_read was drained by its reader's
// lgkm(8) at kt-1 p1, which precedes the kt p0 barrier the stager passed.
// Segments: kt[0,32)->a1 (P1), [32,64)->a2 (P2), merge {a1=P1+P2=zr,
// a2=P2-P1}, [64,96)->a2 (+P3 = zi).  (R0-proven algebra & epilogue.)
// T1 swizzle (R0-proven): mb = wg&31 (A streams), nb = wg>>5 (B L2-shared).
// ---------------------------------------------------------------------------
#define NKT 96

#define MFMA16G(AV, BQ, ACC)                                                \
  __builtin_amdgcn_s_setprio(1);                                            \
  _Pragma("unroll")                                                         \
  for (int mf = 0; mf < 4; ++mf)                                            \
    _Pragma("unroll")                                                       \
    for (int n = 0; n < 4; ++n)                                             \
      ACC[mf][n] = __builtin_amdgcn_mfma_f32_16x16x32_bf16(                 \
          AV[mf], BQ[n], ACC[mf][n], 0, 0, 0);                              \
  __builtin_amdgcn_s_setprio(0);

#define KTBODY(ACC)                                                         \
  {                                                                         \
    const u16* LA = L + (size_t)rb * 8192;                                  \
    int sBw = rb + 1 + (wc >> 1); if (sBw >= 10) sBw -= 10;                 \
    const u16* LBw = L + (size_t)sBw * 8192;                                \
    /* ---- phase 0 ---- */                                                 \
    __builtin_amdgcn_s_barrier();                                           \
    if (kt + 2 < NKT) {                                                     \
      stageA3(kt + 2, ss);                                                  \
      int s1 = ss + 1; if (s1 >= 10) s1 -= 10;                              \
      stageB3(kt + 2, 0, s1);                                               \
    }                                                                       \
    _Pragma("unroll")                                                       \
    for (int mf = 0; mf < 4; ++mf)                                          \
      avB[mf] = *(const bf16x8*)&LA[aoff + 4096 + mf * 128];                \
    _Pragma("unroll")                                                       \
    for (int n = 0; n < 4; ++n)                                             \
      bqB[n] = *(const bf16x8*)&LBw[boff + 4096 + n * 128];                 \
    asm volatile("s_waitcnt lgkmcnt(8)" ::: "memory");                      \
    MFMA16G(avA, bqA, ACC)                                                  \
    /* ---- phase 1 ---- */                                                 \
    if (kt + 2 < NKT) {                                                     \
      int s2 = ss + 2; if (s2 >= 10) s2 -= 10;                              \
      stageB3(kt + 2, 1, s2);                                               \
    }                                                                       \
    if (kt < NKT - 2)       asm volatile("s_waitcnt vmcnt(6)" ::: "memory");\
    else if (kt == NKT - 2) asm volatile("s_waitcnt vmcnt(0)" ::: "memory");\
    __builtin_amdgcn_s_barrier();                                           \
    if (kt + 1 < NKT) {                                                     \
      int rb2 = rb + 3; if (rb2 >= 10) rb2 -= 10;                           \
      const u16* LA2 = L + (size_t)rb2 * 8192;                              \
      int sBw2 = rb2 + 1 + (wc >> 1); if (sBw2 >= 10) sBw2 -= 10;           \
      const u16* LBw2 = L + (size_t)sBw2 * 8192;                            \
      _Pragma("unroll")                                                     \
      for (int mf = 0; mf < 4; ++mf)                                        \
        avA[mf] = *(const bf16x8*)&LA2[aoff + mf * 128];                    \
      _Pragma("unroll")                                                     \
      for (int n = 0; n < 4; ++n)                                           \
        bqA[n] = *(const bf16x8*)&LBw2[boff + n * 128];                     \
      asm volatile("s_waitcnt lgkmcnt(8)" ::: "memory");                    \
    } else {                                                                \
      asm volatile("s_waitcnt lgkmcnt(0)" ::: "memory");                    \
    }                                                                       \
    MFMA16G(avB, bqB, ACC)                                                  \
    rb += 3; if (rb >= 10) rb -= 10;                                        \
    ss += 3; if (ss >= 10) ss -= 10;                                        \
  }

__global__ __launch_bounds__(512, 2) void clstm_gemm_k(
    const u16* __restrict__ X3, const u16* __restrict__ W3,
    const float* __restrict__ cprev, const float* __restrict__ rb_,
    const float* __restrict__ ib_, float* __restrict__ out) {
  __shared__ __align__(16) u16 lds[10][8192];  // 10 regions x 16 KiB = 160 KiB
  const int tid = threadIdx.x;
  const int lane = tid & 63, wave = tid >> 6;
  const int wr = wave >> 2, wc = wave & 3;  // 2M x 4N wave grid
  const int orig = blockIdx.x;
  const int wg = (orig & 7) * 64 + (orig >> 3);  // T1 (512 % 8 == 0)
  const int mb = wg & 31, nb = wg >> 5;  // A streams (32/XCD), B shared (2/XCD)
  const int m0 = mb * 128, n0 = nb * 256;
  const u16* L = &lds[0][0];

  f32x4 a1[4][4] = {}, a2[4][4] = {};  // 2 Gauss banks, 64 f32 each

  // A region [kblk(8)][m(128)][8]; per wave: kblk = wave, 2 x 1 KiB chunks
  auto stageA3 = [&](int kt2, int slot) {
    const u16* s = X3 + ((size_t)(kt2 * 8 + wave) * 4096 + m0 + lane) * 8;
    __builtin_amdgcn_global_load_lds((GAS*)s, (LAS*)&lds[slot][(wave * 128) * 8], 16, 0, 0);
    __builtin_amdgcn_global_load_lds((GAS*)(s + 512), (LAS*)&lds[slot][(wave * 128 + 64) * 8], 16, 0, 0);
  };
  // B half-region [kblk(8)][n(128)][8], hf = 0 (cols n0..) / 1 (n0+128..)
  auto stageB3 = [&](int kt2, int hf, int slot) {
    const u16* s = W3 + ((size_t)(kt2 * 8 + wave) * 4096 + n0 + hf * 128 + lane) * 8;
    __builtin_amdgcn_global_load_lds((GAS*)s, (LAS*)&lds[slot][(wave * 128) * 8], 16, 0, 0);
    __builtin_amdgcn_global_load_lds((GAS*)(s + 512), (LAS*)&lds[slot][(wave * 128 + 64) * 8], 16, 0, 0);
  };

  const int hi = lane >> 4, lo = lane & 15;
  const int aoff = (hi * 128 + wr * 64 + lo) * 8;           // + ks*4096 + mf*128
  const int boff = (hi * 128 + (wc & 1) * 64 + lo) * 8;     // + ks*4096 + n*128

  // ---- prologue: kt0 (slots 0..2) + kt1 (slots 3..5) ----
  stageA3(0, 0); stageB3(0, 0, 1); stageB3(0, 1, 2);
  stageA3(1, 3); stageB3(1, 0, 4); stageB3(1, 1, 5);
  asm volatile("s_waitcnt vmcnt(6)" ::: "memory");  // kt0's 6 loads landed
  __builtin_amdgcn_s_barrier();

  bf16x8 avA[4], avB[4], bqA[4], bqB[4];
  {  // preload kt0 ks0 frag bank
    const u16* LA = L;
    const u16* LBw = L + (size_t)(1 + (wc >> 1)) * 8192;
#pragma unroll
    for (int mf = 0; mf < 4; ++mf) avA[mf] = *(const bf16x8*)&LA[aoff + mf * 128];
#pragma unroll
    for (int n = 0; n < 4; ++n)    bqA[n]  = *(const bf16x8*)&LBw[boff + n * 128];
  }

  int rb = 0, ss = 6, kt;
  for (kt = 0; kt < 32; ++kt) KTBODY(a1)   // segment 1 -> P1
  for (kt = 32; kt < 64; ++kt) KTBODY(a2)  // segment 2 -> P2
  // ---- merge: a1 = P1+P2 (zr-pre), a2 = P2-P1 ----
#pragma unroll
  for (int mf = 0; mf < 4; ++mf)
#pragma unroll
    for (int n = 0; n < 4; ++n) {
      const f32x4 t0 = a1[mf][n];
      a1[mf][n] = t0 + a2[mf][n];
      a2[mf][n] = a2[mf][n] - t0;
    }
  for (kt = 64; kt < NKT; ++kt) KTBODY(a2) // segment 3 -> a2 += P3 = zi-pre

  // ---- fused CLSTM epilogue (R0-proven): zr = a1+rb, zi = a2+ib ----
  const int j = (nb * 4 + wc) * 16 + lo;   // output column in [0,1024)
  float rbias[4], ibias[4];
#pragma unroll
  for (int g = 0; g < 4; ++g) {
    rbias[g] = rb_[g * 1024 + j];
    ibias[g] = ib_[g * 1024 + j];
  }
#pragma unroll
  for (int mf = 0; mf < 4; ++mf) {
    const int rowb = m0 + wr * 64 + mf * 16 + hi * 4;
#pragma unroll
    for (int r = 0; r < 4; ++r) {
      const size_t row = (size_t)(rowb + r);
      // real half: output cols [0,1024)
      {
        const float z0 = a1[mf][0][r] + rbias[0];
        const float z1 = a1[mf][1][r] + rbias[1];
        const float z2 = a1[mf][2][r] + rbias[2];
        const float z3 = a1[mf][3][r] + rbias[3];
        const float ig = fminf(fmaxf(0.2f * z0 + 0.5f, 0.0f), 1.0f);
        const float fg = fminf(fmaxf(0.2f * z1 + 0.5f, 0.0f), 1.0f);
        const float og = fminf(fmaxf(0.2f * z3 + 0.5f, 0.0f), 1.0f);
        const float cp = cprev[row * 2048 + j];
        const float cn = fg * cp + ig * tanhf(z2);
        const float hn = og * tanhf(cn);
        out[row * 2048 + j] = hn;
        out[(size_t)8388608 + row * 2048 + j] = cn;
      }
      // imaginary half: output cols [1024,2048)
      {
        const float z0 = a2[mf][0][r] + ibias[0];
        const float z1 = a2[mf][1][r] + ibias[1];
        const float z2 = a2[mf][2][r] + ibias[2];
        const float z3 = a2[mf][3][r] + ibias[3];
        const float ig = fminf(fmaxf(0.2f * z0 + 0.5f, 0.0f), 1.0f);
        const float fg = fminf(fmaxf(0.2f * z1 + 0.5f, 0.0f), 1.0f);
        const float og = fminf(fmaxf(0.2f * z3 + 0.5f, 0.0f), 1.0f);
        const float cp = cprev[row * 2048 + 1024 + j];
        const float cn = fg * cp + ig * tanhf(z2);
        const float hn = og * tanhf(cn);
        out[row * 2048 + 1024 + j] = hn;
        out[(size_t)8388608 + row * 2048 + 1024 + j] = cn;
      }
    }
  }
}

extern "C" void kernel_launch(void* const* d_in, const int* in_sizes, int n_in,
                              void* d_out, int out_size, void* d_ws, size_t ws_size,
                              hipStream_t stream) {
  const float* inputs = (const float*)d_in[0];
  const float* h_tm1  = (const float*)d_in[1];
  const float* c_tm1  = (const float*)d_in[2];
  const float* Kr     = (const float*)d_in[3];
  const float* Ki     = (const float*)d_in[4];
  const float* Rr     = (const float*)d_in[5];
  const float* Ri     = (const float*)d_in[6];
  const float* rb     = (const float*)d_in[7];
  const float* ib     = (const float*)d_in[8];
  float* out = (float*)d_out;

  u16* X3 = (u16*)d_ws;                       // 768*4096*8 u16 = 48 MiB
  u16* W3 = X3 + (size_t)768 * 4096 * 8;      // 768*4096*8 u16 = 48 MiB

  build_x_k<<<dim3(96, 64), 256, 0, stream>>>(inputs, h_tm1, X3);
  build_w_k<<<dim3(96, 64), 256, 0, stream>>>(Kr, Ki, Rr, Ri, W3);
  clstm_gemm_k<<<dim3(512, 1), 512, 0, stream>>>(X3, W3, c_tm1, rb, ib, out);
}

// Round 7
// 260.647 us; speedup vs baseline: 1.4974x; 1.0899x over previous
//
#include <hip/hip_runtime.h>

typedef unsigned short u16;
typedef unsigned int   u32;

typedef __bf16 bf16x8 __attribute__((ext_vector_type(8)));
typedef float  f32x4  __attribute__((ext_vector_type(4)));

typedef const __attribute__((address_space(1))) u32 GAS;
typedef __attribute__((address_space(3))) u32 LAS;

__device__ __forceinline__ u16 f2bf(float f) {
  u32 u = __builtin_bit_cast(u32, f);
  return (u16)((u + 0x7FFFu + ((u >> 16) & 1u)) >> 16);
}

// Branchless fast tanh: t = 1 - 2/(e^{2|x|}+1), sign restored.
// Overflow-safe (e->inf => t->1).  |err| ~1e-6 << bf16 noise (0.031) and
// test threshold (0.119).  ~7 VALU ops vs ~30 for libm tanhf.
__device__ __forceinline__ float fast_tanh(float x) {
  const float a = fabsf(x);
  const float e = __expf(2.0f * a);
  const float t = 1.0f - 2.0f * __builtin_amdgcn_rcpf(e + 1.0f);
  return copysignf(t, x);
}

// ---------------------------------------------------------------------------
// X3[kblk][m][8] bf16, kblk = k/8, m in [0,4096), k in [0,6144):
//   seg0 [xr | hr], seg1 [xi | hi], seg2 [xr+xi | hr+hi]   (R0-proven)
// ---------------------------------------------------------------------------
__global__ __launch_bounds__(256) void build_x_k(
    const float* __restrict__ inp, const float* __restrict__ h,
    u16* __restrict__ X3) {
  __shared__ float t[64 * 65];  // t[k][m], pitch 65
  const int tid = threadIdx.x;
  const int tx = tid & 15, ty = tid >> 4;
  const int m0 = blockIdx.y * 64, k0 = blockIdx.x * 64;
  const int sel = k0 >> 10;          // uniform per block
  const int kc = k0 & 1023;
  const float* s1 = (sel == 0 || sel == 2 || sel == 4) ? inp : h;
  const int c1 = (sel == 2 || sel == 3) ? (1024 + kc) : kc;
  const bool pair = (sel >= 4);      // add column c1 + 1024 of same source
#pragma unroll
  for (int rr = 0; rr < 4; ++rr) {
    const int m = rr * 16 + ty;
    float4 v = *(const float4*)&s1[(size_t)(m0 + m) * 2048 + c1 + tx * 4];
    if (pair) {
      const float4 w = *(const float4*)&s1[(size_t)(m0 + m) * 2048 + c1 + 1024 + tx * 4];
      v.x += w.x; v.y += w.y; v.z += w.z; v.w += w.w;
    }
    t[(tx * 4 + 0) * 65 + m] = v.x;
    t[(tx * 4 + 1) * 65 + m] = v.y;
    t[(tx * 4 + 2) * 65 + m] = v.z;
    t[(tx * 4 + 3) * 65 + m] = v.w;
  }
  __syncthreads();
#pragma unroll
  for (int rep = 0; rep < 2; ++rep) {
    const int cell = rep * 256 + tid;       // 512 cells: kblk(8) x m(64)
    const int kblk = cell >> 6, m = cell & 63;
    union { u16 s[8]; uint4 v; } tmp;
#pragma unroll
    for (int i = 0; i < 8; ++i) tmp.s[i] = f2bf(t[(kblk * 8 + i) * 65 + m]);
    *(uint4*)&X3[((size_t)(k0 / 8 + kblk) * 4096 + m0 + m) * 8] = tmp.v;
  }
}

// ---------------------------------------------------------------------------
// W3[kblk][n][8] bf16, rows k in [0,6144): seg0 [Kr;Rr], seg1 [Ki;Ri],
// seg2 [Kr-Ki; Rr-Ri].  Cols n = (j>>4)*64 + g*16 + (j&15).   (R0-proven)
// ---------------------------------------------------------------------------
__global__ __launch_bounds__(256) void build_w_k(
    const float* __restrict__ Kr, const float* __restrict__ Ki,
    const float* __restrict__ Rr, const float* __restrict__ Ri,
    u16* __restrict__ W3) {
  __shared__ float t[4 * 1032];  // [g][k(64)][jlo(16)], per-g pitch 1032
  const int tid = threadIdx.x;
  const int tx = tid & 15, ty = tid >> 4;
  const int jhi = blockIdx.y;          // [0,64): 16-j group
  const int k0 = blockIdx.x * 64;      // [0,6144)
  const int sel = k0 >> 10;            // 0:Kr 1:Rr 2:Ki 3:Ri 4:Kr-Ki 5:Rr-Ri
  const int krow = k0 & 1023;
  const int jbase = jhi * 16;
  const float* sA = (sel == 0) ? Kr : (sel == 1) ? Rr : (sel == 2) ? Ki
                  : (sel == 3) ? Ri : (sel == 4) ? Kr : Rr;
  const float* sB = (sel == 4) ? Ki : (sel == 5) ? Ri : nullptr;
#pragma unroll
  for (int g = 0; g < 4; ++g) {
    const int cs = g * 1024 + jbase + tx;
#pragma unroll
    for (int rr = 0; rr < 4; ++rr) {
      const int k = rr * 16 + ty;
      float v = sA[(size_t)(krow + k) * 4096 + cs];
      if (sel >= 4) v -= sB[(size_t)(krow + k) * 4096 + cs];
      t[g * 1032 + k * 16 + tx] = v;
    }
  }
  __syncthreads();
#pragma unroll
  for (int rep = 0; rep < 2; ++rep) {
    const int cell = rep * 256 + tid;       // 512 cells: kblk(8) x n(64)
    const int kblk = cell >> 6, n = cell & 63;
    const int g = n >> 4, jlo = n & 15;
    union { u16 s[8]; uint4 v; } tmp;
#pragma unroll
    for (int i = 0; i < 8; ++i)
      tmp.s[i] = f2bf(t[g * 1032 + (kblk * 8 + i) * 16 + jlo]);
    *(uint4*)&W3[((size_t)(k0 / 8 + kblk) * 4096 + (size_t)jhi * 64 + n) * 8] = tmp.v;
  }
}

// ---------------------------------------------------------------------------
// Gauss 3-product GEMM (M=4096, Kg=6144, Npacked=4096) + fused CLSTM epilogue.
// R7 = R6 frozen (sync skeleton, ring-10, staging identical) + fast_tanh
// epilogue (serial tail shave).  Full design rationale/ledger: see R6.
// ---------------------------------------------------------------------------
#define NKT 96

#define MFMA16G(AV, BQ, ACC)                                                \
  __builtin_amdgcn_s_setprio(1);                                            \
  _Pragma("unroll")                                                         \
  for (int mf = 0; mf < 4; ++mf)                                            \
    _Pragma("unroll")                                                       \
    for (int n = 0; n < 4; ++n)                                             \
      ACC[mf][n] = __builtin_amdgcn_mfma_f32_16x16x32_bf16(                 \
          AV[mf], BQ[n], ACC[mf][n], 0, 0, 0);                              \
  __builtin_amdgcn_s_setprio(0);

#define KTBODY(ACC)                                                         \
  {                                                                         \
    const u16* LA = L + (size_t)rb * 8192;                                  \
    int sBw = rb + 1 + (wc >> 1); if (sBw >= 10) sBw -= 10;                 \
    const u16* LBw = L + (size_t)sBw * 8192;                                \
    /* ---- phase 0 ---- */                                                 \
    __builtin_amdgcn_s_barrier();                                           \
    if (kt + 2 < NKT) {                                                     \
      stageA3(kt + 2, ss);                                                  \
      int s1 = ss + 1; if (s1 >= 10) s1 -= 10;                              \
      stageB3(kt + 2, 0, s1);                                               \
    }                                                                       \
    _Pragma("unroll")                                                       \
    for (int mf = 0; mf < 4; ++mf)                                          \
      avB[mf] = *(const bf16x8*)&LA[aoff + 4096 + mf * 128];                \
    _Pragma("unroll")                                                       \
    for (int n = 0; n < 4; ++n)                                             \
      bqB[n] = *(const bf16x8*)&LBw[boff + 4096 + n * 128];                 \
    asm volatile("s_waitcnt lgkmcnt(8)" ::: "memory");                      \
    MFMA16G(avA, bqA, ACC)                                                  \
    /* ---- phase 1 ---- */                                                 \
    if (kt + 2 < NKT) {                                                     \
      int s2 = ss + 2; if (s2 >= 10) s2 -= 10;                              \
      stageB3(kt + 2, 1, s2);                                               \
    }                                                                       \
    if (kt < NKT - 2)       asm volatile("s_waitcnt vmcnt(6)" ::: "memory");\
    else if (kt == NKT - 2) asm volatile("s_waitcnt vmcnt(0)" ::: "memory");\
    __builtin_amdgcn_s_barrier();                                           \
    if (kt + 1 < NKT) {                                                     \
      int rb2 = rb + 3; if (rb2 >= 10) rb2 -= 10;                           \
      const u16* LA2 = L + (size_t)rb2 * 8192;                              \
      int sBw2 = rb2 + 1 + (wc >> 1); if (sBw2 >= 10) sBw2 -= 10;           \
      const u16* LBw2 = L + (size_t)sBw2 * 8192;                            \
      _Pragma("unroll")                                                     \
      for (int mf = 0; mf < 4; ++mf)                                        \
        avA[mf] = *(const bf16x8*)&LA2[aoff + mf * 128];                    \
      _Pragma("unroll")                                                     \
      for (int n = 0; n < 4; ++n)                                           \
        bqA[n] = *(const bf16x8*)&LBw2[boff + n * 128];                     \
      asm volatile("s_waitcnt lgkmcnt(8)" ::: "memory");                    \
    } else {                                                                \
      asm volatile("s_waitcnt lgkmcnt(0)" ::: "memory");                    \
    }                                                                       \
    MFMA16G(avB, bqB, ACC)                                                  \
    rb += 3; if (rb >= 10) rb -= 10;                                        \
    ss += 3; if (ss >= 10) ss -= 10;                                        \
  }

__global__ __launch_bounds__(512, 2) void clstm_gemm_k(
    const u16* __restrict__ X3, const u16* __restrict__ W3,
    const float* __restrict__ cprev, const float* __restrict__ rb_,
    const float* __restrict__ ib_, float* __restrict__ out) {
  __shared__ __align__(16) u16 lds[10][8192];  // 10 regions x 16 KiB = 160 KiB
  const int tid = threadIdx.x;
  const int lane = tid & 63, wave = tid >> 6;
  const int wr = wave >> 2, wc = wave & 3;  // 2M x 4N wave grid
  const int orig = blockIdx.x;
  const int wg = (orig & 7) * 64 + (orig >> 3);  // T1 (512 % 8 == 0)
  const int mb = wg & 31, nb = wg >> 5;  // A streams (32/XCD), B shared (2/XCD)
  const int m0 = mb * 128, n0 = nb * 256;
  const u16* L = &lds[0][0];

  f32x4 a1[4][4] = {}, a2[4][4] = {};  // 2 Gauss banks, 64 f32 each

  // A region [kblk(8)][m(128)][8]; per wave: kblk = wave, 2 x 1 KiB chunks
  auto stageA3 = [&](int kt2, int slot) {
    const u16* s = X3 + ((size_t)(kt2 * 8 + wave) * 4096 + m0 + lane) * 8;
    __builtin_amdgcn_global_load_lds((GAS*)s, (LAS*)&lds[slot][(wave * 128) * 8], 16, 0, 0);
    __builtin_amdgcn_global_load_lds((GAS*)(s + 512), (LAS*)&lds[slot][(wave * 128 + 64) * 8], 16, 0, 0);
  };
  // B half-region [kblk(8)][n(128)][8], hf = 0 (cols n0..) / 1 (n0+128..)
  auto stageB3 = [&](int kt2, int hf, int slot) {
    const u16* s = W3 + ((size_t)(kt2 * 8 + wave) * 4096 + n0 + hf * 128 + lane) * 8;
    __builtin_amdgcn_global_load_lds((GAS*)s, (LAS*)&lds[slot][(wave * 128) * 8], 16, 0, 0);
    __builtin_amdgcn_global_load_lds((GAS*)(s + 512), (LAS*)&lds[slot][(wave * 128 + 64) * 8], 16, 0, 0);
  };

  const int hi = lane >> 4, lo = lane & 15;
  const int aoff = (hi * 128 + wr * 64 + lo) * 8;           // + ks*4096 + mf*128
  const int boff = (hi * 128 + (wc & 1) * 64 + lo) * 8;     // + ks*4096 + n*128

  // ---- prologue: kt0 (slots 0..2) + kt1 (slots 3..5) ----
  stageA3(0, 0); stageB3(0, 0, 1); stageB3(0, 1, 2);
  stageA3(1, 3); stageB3(1, 0, 4); stageB3(1, 1, 5);
  asm volatile("s_waitcnt vmcnt(6)" ::: "memory");  // kt0's 6 loads landed
  __builtin_amdgcn_s_barrier();

  bf16x8 avA[4], avB[4], bqA[4], bqB[4];
  {  // preload kt0 ks0 frag bank
    const u16* LA = L;
    const u16* LBw = L + (size_t)(1 + (wc >> 1)) * 8192;
#pragma unroll
    for (int mf = 0; mf < 4; ++mf) avA[mf] = *(const bf16x8*)&LA[aoff + mf * 128];
#pragma unroll
    for (int n = 0; n < 4; ++n)    bqA[n]  = *(const bf16x8*)&LBw[boff + n * 128];
  }

  int rb = 0, ss = 6, kt;
  for (kt = 0; kt < 32; ++kt) KTBODY(a1)   // segment 1 -> P1
  for (kt = 32; kt < 64; ++kt) KTBODY(a2)  // segment 2 -> P2
  // ---- merge: a1 = P1+P2 (zr-pre), a2 = P2-P1 ----
#pragma unroll
  for (int mf = 0; mf < 4; ++mf)
#pragma unroll
    for (int n = 0; n < 4; ++n) {
      const f32x4 t0 = a1[mf][n];
      a1[mf][n] = t0 + a2[mf][n];
      a2[mf][n] = a2[mf][n] - t0;
    }
  for (kt = 64; kt < NKT; ++kt) KTBODY(a2) // segment 3 -> a2 += P3 = zi-pre

  // ---- fused CLSTM epilogue (R0-proven layout; fast_tanh this round) ----
  const int j = (nb * 4 + wc) * 16 + lo;   // output column in [0,1024)
  float rbias[4], ibias[4];
#pragma unroll
  for (int g = 0; g < 4; ++g) {
    rbias[g] = rb_[g * 1024 + j];
    ibias[g] = ib_[g * 1024 + j];
  }
#pragma unroll
  for (int mf = 0; mf < 4; ++mf) {
    const int rowb = m0 + wr * 64 + mf * 16 + hi * 4;
#pragma unroll
    for (int r = 0; r < 4; ++r) {
      const size_t row = (size_t)(rowb + r);
      // real half: output cols [0,1024)
      {
        const float z0 = a1[mf][0][r] + rbias[0];
        const float z1 = a1[mf][1][r] + rbias[1];
        const float z2 = a1[mf][2][r] + rbias[2];
        const float z3 = a1[mf][3][r] + rbias[3];
        const float ig = fminf(fmaxf(0.2f * z0 + 0.5f, 0.0f), 1.0f);
        const float fg = fminf(fmaxf(0.2f * z1 + 0.5f, 0.0f), 1.0f);
        const float og = fminf(fmaxf(0.2f * z3 + 0.5f, 0.0f), 1.0f);
        const float cp = cprev[row * 2048 + j];
        const float cn = fg * cp + ig * fast_tanh(z2);
        const float hn = og * fast_tanh(cn);
        out[row * 2048 + j] = hn;
        out[(size_t)8388608 + row * 2048 + j] = cn;
      }
      // imaginary half: output cols [1024,2048)
      {
        const float z0 = a2[mf][0][r] + ibias[0];
        const float z1 = a2[mf][1][r] + ibias[1];
        const float z2 = a2[mf][2][r] + ibias[2];
        const float z3 = a2[mf][3][r] + ibias[3];
        const float ig = fminf(fmaxf(0.2f * z0 + 0.5f, 0.0f), 1.0f);
        const float fg = fminf(fmaxf(0.2f * z1 + 0.5f, 0.0f), 1.0f);
        const float og = fminf(fmaxf(0.2f * z3 + 0.5f, 0.0f), 1.0f);
        const float cp = cprev[row * 2048 + 1024 + j];
        const float cn = fg * cp + ig * fast_tanh(z2);
        const float hn = og * fast_tanh(cn);
        out[row * 2048 + 1024 + j] = hn;
        out[(size_t)8388608 + row * 2048 + 1024 + j] = cn;
      }
    }
  }
}

extern "C" void kernel_launch(void* const* d_in, const int* in_sizes, int n_in,
                              void* d_out, int out_size, void* d_ws, size_t ws_size,
                              hipStream_t stream) {
  const float* inputs = (const float*)d_in[0];
  const float* h_tm1  = (const float*)d_in[1];
  const float* c_tm1  = (const float*)d_in[2];
  const float* Kr     = (const float*)d_in[3];
  const float* Ki     = (const float*)d_in[4];
  const float* Rr     = (const float*)d_in[5];
  const float* Ri     = (const float*)d_in[6];
  const float* rb     = (const float*)d_in[7];
  const float* ib     = (const float*)d_in[8];
  float* out = (float*)d_out;

  u16* X3 = (u16*)d_ws;                       // 768*4096*8 u16 = 48 MiB
  u16* W3 = X3 + (size_t)768 * 4096 * 8;      // 768*4096*8 u16 = 48 MiB

  build_x_k<<<dim3(96, 64), 256, 0, stream>>>(inputs, h_tm1, X3);
  build_w_k<<<dim3(96, 64), 256, 0, stream>>>(Kr, Ki, Rr, Ri, W3);
  clstm_gemm_k<<<dim3(512, 1), 512, 0, stream>>>(X3, W3, c_tm1, rb, ib, out);
}